// Round 12
// baseline (2376.951 us; speedup 1.0000x reference)
//
#include <hip/hip_runtime.h>
#include <hip/hip_bf16.h>

#define NQ 200
#define PFX 5
#define NPATCH 1600
#define NT 1805
#define DM 1024
#define NHEAD 16
#define DHEAD 64
#define NBLK 4
#define NCLS 151
#define NKT 29     // ceil(1805/64) kv tiles
#define NQT 29     // ceil(1805/64) q tiles
#define NWRD 57    // ceil(1805/32) mask words per query row

typedef short s16x8 __attribute__((ext_vector_type(8)));
typedef float f32x4 __attribute__((ext_vector_type(4)));

__device__ __forceinline__ float gelu_f(float x) {
  return 0.5f * x * (1.0f + erff(x * 0.7071067811865476f));
}
__device__ __forceinline__ short f2bf(float x) {
  __hip_bfloat16 h = __float2bfloat16(x);
  return *reinterpret_cast<short*>(&h);
}
__device__ __forceinline__ float bf2f(short s) {
  __hip_bfloat16 h;
  *reinterpret_cast<short*>(&h) = s;
  return __bfloat162float(h);
}
// async 16B global->LDS (width literal 16). LDS dest must be wave-uniform base.
__device__ __forceinline__ void glds16(const void* g, void* l) {
  __builtin_amdgcn_global_load_lds(
      (const __attribute__((address_space(1))) void*)g,
      (__attribute__((address_space(3))) void*)l, 16, 0, 0);
}

// ---------------- concat: x = [q_weight ; x_tokens] ----------------
__global__ __launch_bounds__(256) void concat_kernel(const float* __restrict__ qw,
    const float* __restrict__ xt, float* __restrict__ x) {
  int idx = blockIdx.x * 256 + threadIdx.x;
  if (idx >= NT * DM) return;
  int n = idx >> 10;
  x[idx] = (n < NQ) ? qw[idx] : xt[idx - NQ * DM];
}

// ---------------- LayerNorm -> bf16 hi/lo ----------------
__global__ __launch_bounds__(256) void ln_kernel(const float* __restrict__ in,
    const float* __restrict__ g, const float* __restrict__ b,
    short* __restrict__ oh, short* __restrict__ ol) {
  const int row = blockIdx.x;
  const int tid = threadIdx.x;
  const float* x = in + (size_t)row * DM;
  float v[4];
#pragma unroll
  for (int i = 0; i < 4; ++i) v[i] = x[tid + (i << 8)];
  float s = v[0] + v[1] + v[2] + v[3];
  __shared__ float red[4];
  __shared__ float red2[4];
#pragma unroll
  for (int off = 32; off; off >>= 1) s += __shfl_down(s, off, 64);
  if ((tid & 63) == 0) red[tid >> 6] = s;
  __syncthreads();
  float mean = (red[0] + red[1] + red[2] + red[3]) * (1.0f / DM);
  float sq = 0.f;
#pragma unroll
  for (int i = 0; i < 4; ++i) { float d = v[i] - mean; sq += d * d; }
#pragma unroll
  for (int off = 32; off; off >>= 1) sq += __shfl_down(sq, off, 64);
  if ((tid & 63) == 0) red2[tid >> 6] = sq;
  __syncthreads();
  float var = (red2[0] + red2[1] + red2[2] + red2[3]) * (1.0f / DM);
  float inv = 1.0f / sqrtf(var + 1e-6f);
#pragma unroll
  for (int i = 0; i < 4; ++i) {
    int d = tid + (i << 8);
    float y = (v[i] - mean) * inv * g[d] + b[d];
    short hh = f2bf(y);
    oh[(size_t)row * DM + d] = hh;
    ol[(size_t)row * DM + d] = f2bf(y - bf2f(hh));
  }
}

// ---------------- bf16x3 MFMA GEMM: dbuf LDS + split-K + optional A-lo ----------------
// OMODE: 0 bf16 h/l out (+ACT); 1 fp32 out (+ACT); 2 atomicAdd fp32 (bias z==0);
//        3 partial fp32 at Cf + z*M*N (bias z==0).
template <int BM64, int BSRC, int ALO, int ACT, int OMODE, int KS>
__global__ __launch_bounds__(256) void mgemm_kernel(
    const short* __restrict__ Ah, const short* __restrict__ Al,
    const float* __restrict__ Wf,
    const short* __restrict__ Bh, const short* __restrict__ Bl,
    const float* __restrict__ bias,
    float* __restrict__ Cf, short* __restrict__ Ch, short* __restrict__ Cl,
    int M, int N, int K) {
  constexpr int BM = BM64 ? 64 : 128;
  constexpr int AT = BM64 ? 2 : 4;
  constexpr int AISS = BM64 ? 1 : 2;
  __shared__ __align__(16) short sAh[2 * BM * 32];
  __shared__ __align__(16) short sAl[ALO ? 2 * BM * 32 : 8];
  __shared__ __align__(16) short sBh[2 * 128 * 32], sBl[2 * 128 * 32];
  const int tid = threadIdx.x;
  const int lane = tid & 63;
  const int w = tid >> 6;
  const int bm = blockIdx.y * BM;
  const int bn = blockIdx.x << 7;
  const int z = (KS > 1) ? blockIdx.z : 0;
  const int KL = K / KS;
  const int kbase = z * KL;

  f32x4 acc[AT][4];
  {
    f32x4 zf = {0.f, 0.f, 0.f, 0.f};
#pragma unroll
    for (int mi = 0; mi < AT; ++mi)
#pragma unroll
      for (int ni = 0; ni < 4; ++ni) acc[mi][ni] = zf;
  }

  auto issueA = [&](int buf, int k0) {
#pragma unroll
    for (int i = 0; i < AISS; ++i) {
      int br = (BM64 ? (w << 4) : (w << 5) + (i << 4));
      int r = br + (lane >> 2);
      int cg = (lane & 3) ^ ((r >> 1) & 3);
      size_t go = (size_t)min(bm + r, M - 1) * K + kbase + k0 + (cg << 3);
      glds16(Ah + go, &sAh[(buf * BM + br) * 32]);
      if (ALO) glds16(Al + go, &sAl[(buf * BM + br) * 32]);
    }
  };
  auto issueB1 = [&](int buf, int k0) {
#pragma unroll
    for (int i = 0; i < 2; ++i) {
      int br = (w << 5) + (i << 4);
      int r = br + (lane >> 2);
      int cg = (lane & 3) ^ ((r >> 1) & 3);
      size_t go = (size_t)min(bn + r, N - 1) * K + kbase + k0 + (cg << 3);
      glds16(Bh + go, &sBh[(buf * 128 + br) * 32]);
      glds16(Bl + go, &sBl[(buf * 128 + br) * 32]);
    }
  };
  float wv[2][8];
  auto loadB0 = [&](int k0) {
#pragma unroll
    for (int p = 0; p < 2; ++p) {
      int n = tid & 127;
      int c8 = (tid >> 7) + (p << 1);
      const float* Wp = Wf + (size_t)(kbase + k0 + (c8 << 3)) * N + min(bn + n, N - 1);
#pragma unroll
      for (int j = 0; j < 8; ++j) wv[p][j] = Wp[(size_t)j * N];
    }
  };
  auto writeB0 = [&](int buf) {
#pragma unroll
    for (int p = 0; p < 2; ++p) {
      int n = tid & 127;
      int c8 = (tid >> 7) + (p << 1);
      int cp = c8 ^ ((n >> 1) & 3);
      union { uint4 u; short e[8]; } H, L;
#pragma unroll
      for (int j = 0; j < 8; ++j) {
        short hh = f2bf(wv[p][j]);
        H.e[j] = hh;
        L.e[j] = f2bf(wv[p][j] - bf2f(hh));
      }
      int off = (buf * 128 + n) * 32 + (cp << 3);
      *(uint4*)&sBh[off] = H.u;
      *(uint4*)&sBl[off] = L.u;
    }
  };

  issueA(0, 0);
  if (BSRC == 1) issueB1(0, 0);
  else { loadB0(0); writeB0(0); }
  __syncthreads();

  const int nt = KL >> 5;
  int cur = 0;
  const int ar = lane & 15;
  const int kc = lane >> 4;
  const int wmr = BM64 ? ((w >> 1) << 5) : ((w >> 1) << 6);
  const int wnr = (w & 1) << 6;

  for (int t = 0; t < nt; ++t) {
    const bool more = (t + 1 < nt);
    if (more) {
      int k0n = (t + 1) << 5;
      issueA(cur ^ 1, k0n);
      if (BSRC == 1) issueB1(cur ^ 1, k0n);
      else loadB0(k0n);
    }
    s16x8 fah[AT], fal[AT], fbh[4], fbl[4];
#pragma unroll
    for (int t2 = 0; t2 < AT; ++t2) {
      int r = wmr + (t2 << 4) + ar;
      int off = (cur * BM + r) * 32 + ((kc ^ ((r >> 1) & 3)) << 3);
      fah[t2] = *(const s16x8*)&sAh[off];
      if (ALO) fal[t2] = *(const s16x8*)&sAl[off];
    }
#pragma unroll
    for (int t2 = 0; t2 < 4; ++t2) {
      int r = wnr + (t2 << 4) + ar;
      int off = (cur * 128 + r) * 32 + ((kc ^ ((r >> 1) & 3)) << 3);
      fbh[t2] = *(const s16x8*)&sBh[off];
      fbl[t2] = *(const s16x8*)&sBl[off];
    }
#pragma unroll
    for (int mi = 0; mi < AT; ++mi)
#pragma unroll
      for (int ni = 0; ni < 4; ++ni) {
        acc[mi][ni] = __builtin_amdgcn_mfma_f32_16x16x32_bf16(fah[mi], fbh[ni], acc[mi][ni], 0, 0, 0);
        acc[mi][ni] = __builtin_amdgcn_mfma_f32_16x16x32_bf16(fah[mi], fbl[ni], acc[mi][ni], 0, 0, 0);
        if (ALO)
          acc[mi][ni] = __builtin_amdgcn_mfma_f32_16x16x32_bf16(fal[mi], fbh[ni], acc[mi][ni], 0, 0, 0);
      }
    if (more) {
      if (BSRC == 0) writeB0(cur ^ 1);
      __syncthreads();
      cur ^= 1;
    }
  }

  const int erow = bm + wmr + ((lane >> 4) << 2);
  const int ecol = bn + wnr + (lane & 15);
  float bv[4];
#pragma unroll
  for (int ni = 0; ni < 4; ++ni) {
    int col = ecol + ni * 16;
    float b0 = (bias != nullptr && col < N) ? bias[col] : 0.f;
    bv[ni] = (KS > 1 && z != 0) ? 0.f : b0;
  }
#pragma unroll
  for (int mi = 0; mi < AT; ++mi) {
#pragma unroll
    for (int rr = 0; rr < 4; ++rr) {
      int row = erow + mi * 16 + rr;
      if (row >= M) continue;
#pragma unroll
      for (int ni = 0; ni < 4; ++ni) {
        int col = ecol + ni * 16;
        if (col >= N) continue;
        float v = acc[mi][ni][rr] + bv[ni];
        size_t o = (size_t)row * N + col;
        if (OMODE == 0) {
          if (ACT == 1) v = gelu_f(v);
          short hh = f2bf(v);
          Ch[o] = hh;
          Cl[o] = f2bf(v - bf2f(hh));
        } else if (OMODE == 1) {
          if (ACT == 1) v = gelu_f(v);
          Cf[o] = v;
        } else if (OMODE == 2) {
          atomicAdd(&Cf[o], v);
        } else {
          Cf[(size_t)z * M * N + o] = v;
        }
      }
    }
  }
}

// ---------------- split-K partial reduce (+act, +bf16 hi/lo split) ----------------
template <int ACT, int WSPLIT>
__global__ __launch_bounds__(256) void redsplit_kernel(const float* __restrict__ pb,
    float* __restrict__ outf, short* __restrict__ oh, short* __restrict__ ol,
    int KSr, int MN) {
  int idx = blockIdx.x * 256 + threadIdx.x;
  if (idx >= MN) return;
  float s = 0.f;
  for (int zz = 0; zz < KSr; ++zz) s += pb[(size_t)zz * MN + idx];
  if (ACT == 1) s = gelu_f(s);
  if (WSPLIT) {
    short hh = f2bf(s);
    oh[idx] = hh;
    ol[idx] = f2bf(s - bf2f(hh));
  } else {
    outf[idx] = s;
  }
}

// ---------------- fused gelu + bf16-hi cast (fc1 epilogue) ----------------
__global__ __launch_bounds__(256) void gelusplit_kernel(const float* __restrict__ in,
    short* __restrict__ oh, int n) {
  int idx = (blockIdx.x * 256 + threadIdx.x) << 2;
  if (idx >= n) return;
  float4 v = *(const float4*)(in + idx);
  short4 h;
  h.x = f2bf(gelu_f(v.x));
  h.y = f2bf(gelu_f(v.y));
  h.z = f2bf(gelu_f(v.z));
  h.w = f2bf(gelu_f(v.w));
  *(short4*)(oh + idx) = h;
}

// ---------------- pack attention keep-mask into bits ----------------
__global__ __launch_bounds__(256) void maskpack_kernel(const float* __restrict__ mlog,
    unsigned* __restrict__ bits) {
  int idx = blockIdx.x * 256 + threadIdx.x;
  if (idx >= NQ * NWRD) return;
  int q = idx / NWRD, w = idx - q * NWRD;
  unsigned word = 0u;
  int c0 = w * 32;
#pragma unroll
  for (int b = 0; b < 32; ++b) {
    int c = c0 + b;
    unsigned keep;
    if (c < NQ + PFX) keep = 1u;
    else if (c < NT) keep = (mlog[(size_t)q * NPATCH + (c - NQ - PFX)] > 0.f) ? 1u : 0u;
    else keep = 0u;
    word |= keep << b;
  }
  bits[idx] = word;
}

// ---------------- flash attention, MFMA, KV-split 2 ----------------
// Block = (q-tile 64, head, split). Emits unnormalized O^T partial (fp32) + (m,l).
// QK^T 3-term (Qh·Kh + Qh·Kl + Ql·Kh); PV 1-term (Ph·Vh).
// K/V/P in [64][64]-short LDS tiles with 8-short-chunk XOR swizzle.
__global__ __launch_bounds__(256, 4) void fattn_kernel(
    const short* __restrict__ qh, const short* __restrict__ ql,
    const unsigned* __restrict__ bits,
    float* __restrict__ opart, float2* __restrict__ ml2) {
  const int bid = blockIdx.x;
  const int h = bid & 15;
  const int s = (bid >> 4) & 1;
  const int q0 = (bid >> 5) * 64;
  const int kt0 = s * 15;
  const int kt1 = min(NKT, kt0 + 15);
  const int tid = threadIdx.x;
  const int lane = tid & 63;
  const int w = tid >> 6;
  const int lg = lane >> 4;
  const int lc = lane & 15;

  __shared__ __align__(16) short Kh[64 * 64], Kl[64 * 64];
  __shared__ __align__(16) short Vt[64 * 64];       // V^T hi-only: row d, col kv
  __shared__ __align__(16) short Pp[4][16 * 64];    // per-wave P hi: row q, col kv
  __shared__ float fb[4][16];

  // Q fragments: direct bf16 hi/lo loads
  s16x8 qfh[2], qfl[2];
  {
    int gq = min(q0 + (w << 4) + lc, NT - 1);
    const size_t base = (size_t)gq * 3072 + h * 64;
#pragma unroll
    for (int ks = 0; ks < 2; ++ks) {
      qfh[ks] = *(const s16x8*)(qh + base + ks * 32 + (lg << 3));
      qfl[ks] = *(const s16x8*)(ql + base + ks * 32 + (lg << 3));
    }
  }

  const int krow = tid >> 3, kchk = tid & 7;
  const int vrow = tid >> 2, vchk = tid & 3;
  uint4 pkh[2], pkl[2], pvh[2];
  auto loadKV = [&](int kt) {
#pragma unroll
    for (int ii = 0; ii < 2; ++ii) {
      int gk = kt * 64 + krow + (ii << 5);
      if (gk < NT) {
        size_t b = (size_t)gk * 3072 + 1024 + h * 64 + (kchk << 3);
        pkh[ii] = *(const uint4*)(qh + b);
        pkl[ii] = *(const uint4*)(ql + b);
      } else {
        pkh[ii] = make_uint4(0, 0, 0, 0);
        pkl[ii] = make_uint4(0, 0, 0, 0);
      }
      int gv = kt * 64 + vrow;
      int vc = vchk + (ii << 2);
      if (gv < NT) {
        pvh[ii] = *(const uint4*)(qh + (size_t)gv * 3072 + 2048 + h * 64 + (vc << 3));
      } else {
        pvh[ii] = make_uint4(0, 0, 0, 0);
      }
    }
  };
  auto writeKV = [&]() {
#pragma unroll
    for (int ii = 0; ii < 2; ++ii) {
      int row = krow + (ii << 5);
      int off = (row << 6) + ((kchk ^ (row & 7)) << 3);
      *(uint4*)&Kh[off] = pkh[ii];
      *(uint4*)&Kl[off] = pkl[ii];
      int vc = vchk + (ii << 2);
      const short* vs = (const short*)&pvh[ii];
#pragma unroll
      for (int jj = 0; jj < 8; ++jj) {
        int d = (vc << 3) + jj;
        Vt[(d << 6) + (((vrow >> 3) ^ (d & 7)) << 3) + (vrow & 7)] = vs[jj];
      }
    }
  };

  float rm_r[4], rl_r[4];
#pragma unroll
  for (int r = 0; r < 4; ++r) { rm_r[r] = -3.0e38f; rl_r[r] = 0.f; }
  f32x4 o_acc[4];
  {
    f32x4 zf = {0.f, 0.f, 0.f, 0.f};
#pragma unroll
    for (int nd = 0; nd < 4; ++nd) o_acc[nd] = zf;
  }

  loadKV(kt0);
  for (int kt = kt0; kt < kt1; ++kt) {
    __syncthreads();
    writeKV();
    __syncthreads();
    if (kt + 1 < kt1) loadKV(kt + 1);

    // ---- QK^T (3-term) ----
    f32x4 sc[4];
    {
      f32x4 zf = {0.f, 0.f, 0.f, 0.f};
#pragma unroll
      for (int ni = 0; ni < 4; ++ni) sc[ni] = zf;
    }
    __builtin_amdgcn_s_setprio(1);
#pragma unroll
    for (int ni = 0; ni < 4; ++ni) {
#pragma unroll
      for (int ks = 0; ks < 2; ++ks) {
        int row = (ni << 4) + lc;
        int ch = ((ks << 2) + lg) ^ (row & 7);
        s16x8 kh = *(const s16x8*)&Kh[(row << 6) + (ch << 3)];
        s16x8 kl = *(const s16x8*)&Kl[(row << 6) + (ch << 3)];
        sc[ni] = __builtin_amdgcn_mfma_f32_16x16x32_bf16(qfh[ks], kh, sc[ni], 0, 0, 0);
        sc[ni] = __builtin_amdgcn_mfma_f32_16x16x32_bf16(qfh[ks], kl, sc[ni], 0, 0, 0);
        sc[ni] = __builtin_amdgcn_mfma_f32_16x16x32_bf16(qfl[ks], kh, sc[ni], 0, 0, 0);
      }
    }
    __builtin_amdgcn_s_setprio(0);

    // ---- scale + mask + OOB ----
    unsigned wr0[4], wr1[4];
#pragma unroll
    for (int r = 0; r < 4; ++r) {
      int gq = q0 + (w << 4) + (lg << 2) + r;
      wr0[r] = 0xFFFFFFFFu; wr1[r] = 0xFFFFFFFFu;
      if (gq < NQ) {
        wr0[r] = bits[gq * NWRD + (kt << 1)];
        wr1[r] = ((kt << 1) + 1 < NWRD) ? bits[gq * NWRD + (kt << 1) + 1] : 0u;
      }
    }
    const int kvb = kt << 6;
#pragma unroll
    for (int ni = 0; ni < 4; ++ni) {
      int kv = kvb + (ni << 4) + lc;
      unsigned bitpos = ((ni & 1) << 4) + lc;
#pragma unroll
      for (int r = 0; r < 4; ++r) {
        float sv = sc[ni][r] * 0.125f;
        unsigned wd = (ni < 2) ? wr0[r] : wr1[r];
        if (!((wd >> bitpos) & 1u)) sv -= 1e9f;
        sc[ni][r] = (kv < NT) ? sv : -3.0e38f;
      }
    }

    // ---- online softmax ----
    float fr[4];
#pragma unroll
    for (int r = 0; r < 4; ++r) {
      float tm = fmaxf(fmaxf(sc[0][r], sc[1][r]), fmaxf(sc[2][r], sc[3][r]));
#pragma unroll
      for (int m2 = 1; m2 < 16; m2 <<= 1) tm = fmaxf(tm, __shfl_xor(tm, m2, 64));
      float mnew = fmaxf(rm_r[r], tm);
      float f = __expf(rm_r[r] - mnew);
      float ps = 0.f;
#pragma unroll
      for (int ni = 0; ni < 4; ++ni) {
        float e = __expf(sc[ni][r] - mnew);
        sc[ni][r] = e;
        ps += e;
      }
#pragma unroll
      for (int m2 = 1; m2 < 16; m2 <<= 1) ps += __shfl_xor(ps, m2, 64);
      rm_r[r] = mnew;
      rl_r[r] = rl_r[r] * f + ps;
      fr[r] = f;
    }

    // ---- P (hi only) -> per-wave LDS tile ----
    short* P = Pp[w];
#pragma unroll
    for (int ni = 0; ni < 4; ++ni) {
#pragma unroll
      for (int r = 0; r < 4; ++r) {
        int qq = (lg << 2) + r;
        int col = (ni << 4) + lc;
        P[(qq << 6) + (((col >> 3) ^ (qq & 7)) << 3) + (col & 7)] = f2bf(sc[ni][r]);
      }
    }
    if (lc == 0) {
#pragma unroll
      for (int r = 0; r < 4; ++r) fb[w][(lg << 2) + r] = fr[r];
    }
    float fq = fb[w][lc];
#pragma unroll
    for (int nd = 0; nd < 4; ++nd)
#pragma unroll
      for (int r = 0; r < 4; ++r) o_acc[nd][r] *= fq;

    // ---- PV: O^T = V^T_h @ P^T_h (direct b128 frag reads) ----
    s16x8 pfrag[2];
#pragma unroll
    for (int ks = 0; ks < 2; ++ks)
      pfrag[ks] = *(const s16x8*)&P[(lc << 6) + ((((ks << 2) + lg) ^ (lc & 7)) << 3)];
    __builtin_amdgcn_s_setprio(1);
#pragma unroll
    for (int nd = 0; nd < 4; ++nd) {
      int row = (nd << 4) + lc;
#pragma unroll
      for (int ks = 0; ks < 2; ++ks) {
        s16x8 vh = *(const s16x8*)&Vt[(row << 6) + ((((ks << 2) + lg) ^ (lc & 7)) << 3)];
        o_acc[nd] = __builtin_amdgcn_mfma_f32_16x16x32_bf16(vh, pfrag[ks], o_acc[nd], 0, 0, 0);
      }
    }
    __builtin_amdgcn_s_setprio(0);
  }

  // ---- epilogue: unnormalized partial O + per-row (m, l) ----
  if (lc == 0) {
    float2* mlp = ml2 + ((s << 4) + h) * NT;
#pragma unroll
    for (int r = 0; r < 4; ++r) {
      int gq = q0 + (w << 4) + (lg << 2) + r;
      if (gq < NT) mlp[gq] = make_float2(rm_r[r], rl_r[r]);
    }
  }
  int gq = q0 + (w << 4) + lc;
  if (gq < NT) {
    float* op = opart + (size_t)s * NT * DM + (size_t)gq * DM + h * 64;
#pragma unroll
    for (int nd = 0; nd < 4; ++nd)
      *(float4*)(op + (nd << 4) + (lg << 2)) = *(float4*)&o_acc[nd];
  }
}

// ---------------- flash-merge of 2 KV-split partials -> bf16 h/l ----------------
__global__ __launch_bounds__(256) void attncomb_kernel(
    const float* __restrict__ opart, const float2* __restrict__ ml2,
    short* __restrict__ aoh, short* __restrict__ aol) {
  int f = (blockIdx.x * 256 + threadIdx.x) << 2;   // flat over NT*DM (exact grid)
  int n = f >> 10;
  int h = (f & 1023) >> 6;
  float2 a = ml2[h * NT + n];
  float2 b = ml2[(16 + h) * NT + n];
  float m = fmaxf(a.x, b.x);
  float w0 = __expf(a.x - m), w1 = __expf(b.x - m);
  float inv = 1.0f / (w0 * a.y + w1 * b.y);
  float4 o0 = *(const float4*)(opart + f);
  float4 o1 = *(const float4*)(opart + (size_t)NT * DM + f);
  float ov[4] = {(o0.x * w0 + o1.x * w1) * inv, (o0.y * w0 + o1.y * w1) * inv,
                 (o0.z * w0 + o1.z * w1) * inv, (o0.w * w0 + o1.w * w1) * inv};
  short hh[4], ll[4];
#pragma unroll
  for (int j = 0; j < 4; ++j) {
    hh[j] = f2bf(ov[j]);
    ll[j] = f2bf(ov[j] - bf2f(hh[j]));
  }
  *(short4*)(aoh + f) = make_short4(hh[0], hh[1], hh[2], hh[3]);
  *(short4*)(aol + f) = make_short4(ll[0], ll[1], ll[2], ll[3]);
}

// ---------------- residual with layer-scale: x += ls * y ----------------
__global__ __launch_bounds__(256) void resid_kernel(float* __restrict__ x,
    const float* __restrict__ y, const float* __restrict__ ls) {
  int idx = blockIdx.x * 256 + threadIdx.x;
  if (idx >= NT * DM) return;
  int d = idx & (DM - 1);
  x[idx] = fmaf(ls[d], y[idx], x[idx]);
}

extern "C" void kernel_launch(void* const* d_in, const int* in_sizes, int n_in,
                              void* d_out, int out_size, void* d_ws, size_t ws_size,
                              hipStream_t stream) {
  const float* x_tokens = (const float*)d_in[0];
  const float* q_weight = (const float*)d_in[1];
  const float* norm_g   = (const float*)d_in[2];
  const float* norm_b   = (const float*)d_in[3];
  const float* class_W  = (const float*)d_in[4];
  const float* class_b  = (const float*)d_in[5];
  const float* mask_W1  = (const float*)d_in[6];
  const float* mask_b1  = (const float*)d_in[7];
  const float* mask_W2  = (const float*)d_in[8];
  const float* mask_b2  = (const float*)d_in[9];
  const float* mask_W3  = (const float*)d_in[10];
  const float* mask_b3  = (const float*)d_in[11];
  const float* ln1_g    = (const float*)d_in[12];
  const float* ln1_b    = (const float*)d_in[13];
  const float* ln2_g    = (const float*)d_in[14];
  const float* ln2_b    = (const float*)d_in[15];
  const float* qkv_W    = (const float*)d_in[16];
  const float* qkv_b    = (const float*)d_in[17];
  const float* proj_W   = (const float*)d_in[18];
  const float* proj_b   = (const float*)d_in[19];
  const float* ls1      = (const float*)d_in[20];
  const float* ls2      = (const float*)d_in[21];
  const float* fc1_W    = (const float*)d_in[22];
  const float* fc1_b    = (const float*)d_in[23];
  const float* fc2_W    = (const float*)d_in[24];
  const float* fc2_b    = (const float*)d_in[25];

  float* out = (float*)d_out;

  // ---- workspace carve: ~59.7 MB total (< 60.86 proven) ----
  char* p = (char*)d_ws;
  auto alloc = [&](size_t bytes) {
    char* r = p;
    p += (bytes + 255) & ~(size_t)255;
    return r;
  };
  float* x     = (float*)alloc((size_t)NT * DM * 4);       // 7.39
  short* lnb_h = (short*)alloc((size_t)NT * DM * 2);       // 3.70 } ao h/l + fc2o overlay
  short* lnb_l = (short*)alloc((size_t)NT * DM * 2);       // 3.70 }
  char*  A1    = alloc((size_t)NT * 4 * DM * 4);           // 29.57: qkv h/l | fc1acc | predict
  char*  A2    = alloc((size_t)NT * 4 * DM * 2);           // 14.78: Opart[2] | projo | g1h
  unsigned* bias_bits = (unsigned*)alloc((size_t)NQ * NWRD * 4);
  float2* ml2  = (float2*)alloc((size_t)2 * 16 * NT * 8);  // 0.46

  short* qkvh   = (short*)A1;                        // NT*3DM shorts (11.09)
  short* qkvl   = qkvh + (size_t)NT * 3 * DM;        // NT*3DM shorts (11.09)
  float* fc1acc = (float*)A1;                        // NT*4DM fp32 (29.57)
  short* f1_h = (short*)A1;                          // predict scratch (first 2.46 MB)
  short* f1_l = f1_h + (size_t)NQ * DM;
  short* f2_h = f1_l + (size_t)NQ * DM;
  short* f2_l = f2_h + (size_t)NQ * DM;
  short* f3_h = f2_l + (size_t)NQ * DM;
  short* f3_l = f3_h + (size_t)NQ * DM;
  float* pbuf = (float*)(A1 + ((size_t)4 << 20));    // partials at A1+4MB (<=6.55MB)
  float* opart = (float*)A2;                         // 2 x NT*DM fp32 (exact fit)
  float* projo = (float*)(A2 + (size_t)NT * DM * 4); // NT*DM fp32 (upper half, after comb)
  short* g1h   = (short*)A2;                         // NT*4DM shorts (full A2, after proj)
  short* aoh   = lnb_h;                              // combine output (lnb dead by then)
  short* aol   = lnb_l;
  float* fc2o  = (float*)lnb_h;                      // NT*DM fp32 (lnb dead again)

  const int ELEM_GRID = (NT * DM + 255) / 256;
  auto g128 = [](int M, int Nc, int ks) { return dim3((Nc + 127) / 128, (M + 127) / 128, ks); };
  auto g64  = [](int M, int Nc, int ks) { return dim3((Nc + 127) / 128, (M + 63) / 64, ks); };
  auto rgrid = [](int n) { return dim3((n + 255) / 256); };

  concat_kernel<<<ELEM_GRID, 256, 0, stream>>>(q_weight, x_tokens, x);

  for (int i = 0; i <= NBLK; ++i) {
    // ---- predict head on shared-norm LN(x) ----
    ln_kernel<<<NT, 256, 0, stream>>>(x, norm_g, norm_b, lnb_h, lnb_l);
    float* mask_i = out + (size_t)i * NQ * NPATCH;
    float* cls_i  = out + (size_t)5 * NQ * NPATCH + (size_t)i * NQ * NCLS;
    mgemm_kernel<1, 0, 1, 0, 3, 8><<<g64(NQ, DM, 8), 256, 0, stream>>>(
        lnb_h, lnb_l, mask_W1, nullptr, nullptr, mask_b1, pbuf, nullptr, nullptr, NQ, DM, DM);
    redsplit_kernel<1, 1><<<rgrid(NQ * DM), 256, 0, stream>>>(pbuf, nullptr, f1_h, f1_l, 8, NQ * DM);
    mgemm_kernel<1, 0, 1, 0, 3, 8><<<g64(NQ, DM, 8), 256, 0, stream>>>(
        f1_h, f1_l, mask_W2, nullptr, nullptr, mask_b2, pbuf, nullptr, nullptr, NQ, DM, DM);
    redsplit_kernel<1, 1><<<rgrid(NQ * DM), 256, 0, stream>>>(pbuf, nullptr, f2_h, f2_l, 8, NQ * DM);
    mgemm_kernel<1, 0, 1, 0, 3, 8><<<g64(NQ, DM, 8), 256, 0, stream>>>(
        f2_h, f2_l, mask_W3, nullptr, nullptr, mask_b3, pbuf, nullptr, nullptr, NQ, DM, DM);
    redsplit_kernel<0, 1><<<rgrid(NQ * DM), 256, 0, stream>>>(pbuf, nullptr, f3_h, f3_l, 8, NQ * DM);
    mgemm_kernel<1, 1, 1, 0, 3, 4><<<g64(NQ, NPATCH, 4), 256, 0, stream>>>(
        f3_h, f3_l, nullptr, lnb_h + (size_t)(NQ + PFX) * DM, lnb_l + (size_t)(NQ + PFX) * DM,
        nullptr, pbuf, nullptr, nullptr, NQ, NPATCH, DM);
    redsplit_kernel<0, 0><<<rgrid(NQ * NPATCH), 256, 0, stream>>>(
        pbuf, mask_i, nullptr, nullptr, 4, NQ * NPATCH);
    mgemm_kernel<1, 0, 1, 0, 3, 8><<<g64(NQ, NCLS, 8), 256, 0, stream>>>(
        lnb_h, lnb_l, class_W, nullptr, nullptr, class_b, pbuf, nullptr, nullptr, NQ, NCLS, DM);
    redsplit_kernel<0, 0><<<rgrid(NQ * NCLS), 256, 0, stream>>>(
        pbuf, cls_i, nullptr, nullptr, 8, NQ * NCLS);
    if (i == NBLK) break;

    // ---- transformer block i ----
    ln_kernel<<<NT, 256, 0, stream>>>(x, ln1_g + i * DM, ln1_b + i * DM, lnb_h, lnb_l);
    mgemm_kernel<0, 0, 1, 0, 0, 1><<<g128(NT, 3 * DM, 1), 256, 0, stream>>>(
        lnb_h, lnb_l, qkv_W + (size_t)i * DM * 3 * DM, nullptr, nullptr,
        qkv_b + i * 3 * DM, nullptr, qkvh, qkvl, NT, 3 * DM, DM);
    maskpack_kernel<<<(NQ * NWRD + 255) / 256, 256, 0, stream>>>(mask_i, bias_bits);
    fattn_kernel<<<NQT * NHEAD * 2, 256, 0, stream>>>(qkvh, qkvl, bias_bits, opart, ml2);
    attncomb_kernel<<<NT, 256, 0, stream>>>(opart, ml2, aoh, aol);
    hipMemsetAsync(projo, 0, (size_t)NT * DM * 4, stream);
    mgemm_kernel<1, 0, 1, 0, 2, 4><<<g64(NT, DM, 4), 256, 0, stream>>>(
        aoh, aol, proj_W + (size_t)i * DM * DM, nullptr, nullptr,
        proj_b + i * DM, projo, nullptr, nullptr, NT, DM, DM);
    resid_kernel<<<ELEM_GRID, 256, 0, stream>>>(x, projo, ls1 + i * DM);
    ln_kernel<<<NT, 256, 0, stream>>>(x, ln2_g + i * DM, ln2_b + i * DM, lnb_h, lnb_l);
    hipMemsetAsync(fc1acc, 0, (size_t)NT * 4 * DM * 4, stream);
    mgemm_kernel<0, 0, 1, 0, 2, 2><<<g128(NT, 4 * DM, 2), 256, 0, stream>>>(
        lnb_h, lnb_l, fc1_W + (size_t)i * DM * 4 * DM, nullptr, nullptr,
        fc1_b + i * 4 * DM, fc1acc, nullptr, nullptr, NT, 4 * DM, DM);
    gelusplit_kernel<<<rgrid(NT * DM), 256, 0, stream>>>(fc1acc, g1h, NT * 4 * DM);
    hipMemsetAsync(fc2o, 0, (size_t)NT * DM * 4, stream);
    mgemm_kernel<1, 0, 0, 0, 2, 4><<<g64(NT, DM, 4), 256, 0, stream>>>(
        g1h, nullptr, fc2_W + (size_t)i * 4 * DM * DM, nullptr, nullptr,
        fc2_b + i * DM, fc2o, nullptr, nullptr, NT, DM, 4 * DM);
    resid_kernel<<<ELEM_GRID, 256, 0, stream>>>(x, fc2o, ls2 + i * DM);
  }
}

// Round 13
// 1947.518 us; speedup vs baseline: 1.2205x; 1.2205x over previous
//
#include <hip/hip_runtime.h>
#include <hip/hip_bf16.h>

#define NQ 200
#define PFX 5
#define NPATCH 1600
#define NT 1805
#define DM 1024
#define NHEAD 16
#define DHEAD 64
#define NBLK 4
#define NCLS 151
#define NKT 29     // ceil(1805/64) kv tiles
#define NWRD 57    // ceil(1805/32) mask words per query row

typedef short s16x8 __attribute__((ext_vector_type(8)));
typedef float f32x4 __attribute__((ext_vector_type(4)));

__device__ __forceinline__ float gelu_f(float x) {
  return 0.5f * x * (1.0f + erff(x * 0.7071067811865476f));
}
__device__ __forceinline__ short f2bf(float x) {
  __hip_bfloat16 h = __float2bfloat16(x);
  return *reinterpret_cast<short*>(&h);
}
__device__ __forceinline__ float bf2f(short s) {
  __hip_bfloat16 h;
  *reinterpret_cast<short*>(&h) = s;
  return __bfloat162float(h);
}
// async 16B global->LDS (width literal 16). LDS dest must be wave-uniform base.
__device__ __forceinline__ void glds16(const void* g, void* l) {
  __builtin_amdgcn_global_load_lds(
      (const __attribute__((address_space(1))) void*)g,
      (__attribute__((address_space(3))) void*)l, 16, 0, 0);
}

// ---------------- concat: x = [q_weight ; x_tokens] ----------------
__global__ __launch_bounds__(256) void concat_kernel(const float* __restrict__ qw,
    const float* __restrict__ xt, float* __restrict__ x) {
  int idx = blockIdx.x * 256 + threadIdx.x;
  if (idx >= NT * DM) return;
  int n = idx >> 10;
  x[idx] = (n < NQ) ? qw[idx] : xt[idx - NQ * DM];
}

// ---------------- LayerNorm -> bf16 hi/lo ----------------
__global__ __launch_bounds__(256) void ln_kernel(const float* __restrict__ in,
    const float* __restrict__ g, const float* __restrict__ b,
    short* __restrict__ oh, short* __restrict__ ol) {
  const int row = blockIdx.x;
  const int tid = threadIdx.x;
  const float* x = in + (size_t)row * DM;
  float v[4];
#pragma unroll
  for (int i = 0; i < 4; ++i) v[i] = x[tid + (i << 8)];
  float s = v[0] + v[1] + v[2] + v[3];
  __shared__ float red[4];
  __shared__ float red2[4];
#pragma unroll
  for (int off = 32; off; off >>= 1) s += __shfl_down(s, off, 64);
  if ((tid & 63) == 0) red[tid >> 6] = s;
  __syncthreads();
  float mean = (red[0] + red[1] + red[2] + red[3]) * (1.0f / DM);
  float sq = 0.f;
#pragma unroll
  for (int i = 0; i < 4; ++i) { float d = v[i] - mean; sq += d * d; }
#pragma unroll
  for (int off = 32; off; off >>= 1) sq += __shfl_down(sq, off, 64);
  if ((tid & 63) == 0) red2[tid >> 6] = sq;
  __syncthreads();
  float var = (red2[0] + red2[1] + red2[2] + red2[3]) * (1.0f / DM);
  float inv = 1.0f / sqrtf(var + 1e-6f);
#pragma unroll
  for (int i = 0; i < 4; ++i) {
    int d = tid + (i << 8);
    float y = (v[i] - mean) * inv * g[d] + b[d];
    short hh = f2bf(y);
    oh[(size_t)row * DM + d] = hh;
    ol[(size_t)row * DM + d] = f2bf(y - bf2f(hh));
  }
}

// ---------------- bf16x3 MFMA GEMM: dbuf LDS + split-K + optional A-lo ----------------
// OMODE: 0 bf16 h/l out (+ACT); 1 fp32 out (+ACT); 2 atomicAdd fp32 (bias z==0);
//        3 partial fp32 at Cf + z*M*N (bias z==0).
template <int BM64, int BSRC, int ALO, int ACT, int OMODE, int KS>
__global__ __launch_bounds__(256) void mgemm_kernel(
    const short* __restrict__ Ah, const short* __restrict__ Al,
    const float* __restrict__ Wf,
    const short* __restrict__ Bh, const short* __restrict__ Bl,
    const float* __restrict__ bias,
    float* __restrict__ Cf, short* __restrict__ Ch, short* __restrict__ Cl,
    int M, int N, int K) {
  constexpr int BM = BM64 ? 64 : 128;
  constexpr int AT = BM64 ? 2 : 4;
  constexpr int AISS = BM64 ? 1 : 2;
  __shared__ __align__(16) short sAh[2 * BM * 32];
  __shared__ __align__(16) short sAl[ALO ? 2 * BM * 32 : 8];
  __shared__ __align__(16) short sBh[2 * 128 * 32], sBl[2 * 128 * 32];
  const int tid = threadIdx.x;
  const int lane = tid & 63;
  const int w = tid >> 6;
  const int bm = blockIdx.y * BM;
  const int bn = blockIdx.x << 7;
  const int z = (KS > 1) ? blockIdx.z : 0;
  const int KL = K / KS;
  const int kbase = z * KL;

  f32x4 acc[AT][4];
  {
    f32x4 zf = {0.f, 0.f, 0.f, 0.f};
#pragma unroll
    for (int mi = 0; mi < AT; ++mi)
#pragma unroll
      for (int ni = 0; ni < 4; ++ni) acc[mi][ni] = zf;
  }

  auto issueA = [&](int buf, int k0) {
#pragma unroll
    for (int i = 0; i < AISS; ++i) {
      int br = (BM64 ? (w << 4) : (w << 5) + (i << 4));
      int r = br + (lane >> 2);
      int cg = (lane & 3) ^ ((r >> 1) & 3);
      size_t go = (size_t)min(bm + r, M - 1) * K + kbase + k0 + (cg << 3);
      glds16(Ah + go, &sAh[(buf * BM + br) * 32]);
      if (ALO) glds16(Al + go, &sAl[(buf * BM + br) * 32]);
    }
  };
  auto issueB1 = [&](int buf, int k0) {
#pragma unroll
    for (int i = 0; i < 2; ++i) {
      int br = (w << 5) + (i << 4);
      int r = br + (lane >> 2);
      int cg = (lane & 3) ^ ((r >> 1) & 3);
      size_t go = (size_t)min(bn + r, N - 1) * K + kbase + k0 + (cg << 3);
      glds16(Bh + go, &sBh[(buf * 128 + br) * 32]);
      glds16(Bl + go, &sBl[(buf * 128 + br) * 32]);
    }
  };
  float wv[2][8];
  auto loadB0 = [&](int k0) {
#pragma unroll
    for (int p = 0; p < 2; ++p) {
      int n = tid & 127;
      int c8 = (tid >> 7) + (p << 1);
      const float* Wp = Wf + (size_t)(kbase + k0 + (c8 << 3)) * N + min(bn + n, N - 1);
#pragma unroll
      for (int j = 0; j < 8; ++j) wv[p][j] = Wp[(size_t)j * N];
    }
  };
  auto writeB0 = [&](int buf) {
#pragma unroll
    for (int p = 0; p < 2; ++p) {
      int n = tid & 127;
      int c8 = (tid >> 7) + (p << 1);
      int cp = c8 ^ ((n >> 1) & 3);
      union { uint4 u; short e[8]; } H, L;
#pragma unroll
      for (int j = 0; j < 8; ++j) {
        short hh = f2bf(wv[p][j]);
        H.e[j] = hh;
        L.e[j] = f2bf(wv[p][j] - bf2f(hh));
      }
      int off = (buf * 128 + n) * 32 + (cp << 3);
      *(uint4*)&sBh[off] = H.u;
      *(uint4*)&sBl[off] = L.u;
    }
  };

  issueA(0, 0);
  if (BSRC == 1) issueB1(0, 0);
  else { loadB0(0); writeB0(0); }
  __syncthreads();

  const int nt = KL >> 5;
  int cur = 0;
  const int ar = lane & 15;
  const int kc = lane >> 4;
  const int wmr = BM64 ? ((w >> 1) << 5) : ((w >> 1) << 6);
  const int wnr = (w & 1) << 6;

  for (int t = 0; t < nt; ++t) {
    const bool more = (t + 1 < nt);
    if (more) {
      int k0n = (t + 1) << 5;
      issueA(cur ^ 1, k0n);
      if (BSRC == 1) issueB1(cur ^ 1, k0n);
      else loadB0(k0n);
    }
    s16x8 fah[AT], fal[AT], fbh[4], fbl[4];
#pragma unroll
    for (int t2 = 0; t2 < AT; ++t2) {
      int r = wmr + (t2 << 4) + ar;
      int off = (cur * BM + r) * 32 + ((kc ^ ((r >> 1) & 3)) << 3);
      fah[t2] = *(const s16x8*)&sAh[off];
      if (ALO) fal[t2] = *(const s16x8*)&sAl[off];
    }
#pragma unroll
    for (int t2 = 0; t2 < 4; ++t2) {
      int r = wnr + (t2 << 4) + ar;
      int off = (cur * 128 + r) * 32 + ((kc ^ ((r >> 1) & 3)) << 3);
      fbh[t2] = *(const s16x8*)&sBh[off];
      fbl[t2] = *(const s16x8*)&sBl[off];
    }
#pragma unroll
    for (int mi = 0; mi < AT; ++mi)
#pragma unroll
      for (int ni = 0; ni < 4; ++ni) {
        acc[mi][ni] = __builtin_amdgcn_mfma_f32_16x16x32_bf16(fah[mi], fbh[ni], acc[mi][ni], 0, 0, 0);
        acc[mi][ni] = __builtin_amdgcn_mfma_f32_16x16x32_bf16(fah[mi], fbl[ni], acc[mi][ni], 0, 0, 0);
        if (ALO)
          acc[mi][ni] = __builtin_amdgcn_mfma_f32_16x16x32_bf16(fal[mi], fbh[ni], acc[mi][ni], 0, 0, 0);
      }
    if (more) {
      if (BSRC == 0) writeB0(cur ^ 1);
      __syncthreads();
      cur ^= 1;
    }
  }

  const int erow = bm + wmr + ((lane >> 4) << 2);
  const int ecol = bn + wnr + (lane & 15);
  float bv[4];
#pragma unroll
  for (int ni = 0; ni < 4; ++ni) {
    int col = ecol + ni * 16;
    float b0 = (bias != nullptr && col < N) ? bias[col] : 0.f;
    bv[ni] = (KS > 1 && z != 0) ? 0.f : b0;
  }
#pragma unroll
  for (int mi = 0; mi < AT; ++mi) {
#pragma unroll
    for (int rr = 0; rr < 4; ++rr) {
      int row = erow + mi * 16 + rr;
      if (row >= M) continue;
#pragma unroll
      for (int ni = 0; ni < 4; ++ni) {
        int col = ecol + ni * 16;
        if (col >= N) continue;
        float v = acc[mi][ni][rr] + bv[ni];
        size_t o = (size_t)row * N + col;
        if (OMODE == 0) {
          if (ACT == 1) v = gelu_f(v);
          short hh = f2bf(v);
          Ch[o] = hh;
          Cl[o] = f2bf(v - bf2f(hh));
        } else if (OMODE == 1) {
          if (ACT == 1) v = gelu_f(v);
          Cf[o] = v;
        } else if (OMODE == 2) {
          atomicAdd(&Cf[o], v);
        } else {
          Cf[(size_t)z * M * N + o] = v;
        }
      }
    }
  }
}

// ---------------- split-K partial reduce (+act, +bf16 hi/lo split) ----------------
template <int ACT, int WSPLIT>
__global__ __launch_bounds__(256) void redsplit_kernel(const float* __restrict__ pb,
    float* __restrict__ outf, short* __restrict__ oh, short* __restrict__ ol,
    int KSr, int MN) {
  int idx = blockIdx.x * 256 + threadIdx.x;
  if (idx >= MN) return;
  float s = 0.f;
  for (int zz = 0; zz < KSr; ++zz) s += pb[(size_t)zz * MN + idx];
  if (ACT == 1) s = gelu_f(s);
  if (WSPLIT) {
    short hh = f2bf(s);
    oh[idx] = hh;
    ol[idx] = f2bf(s - bf2f(hh));
  } else {
    outf[idx] = s;
  }
}

// ---------------- fused gelu + bf16-hi cast (fc1 epilogue) ----------------
__global__ __launch_bounds__(256) void gelusplit_kernel(const float* __restrict__ in,
    short* __restrict__ oh, int n) {
  int idx = (blockIdx.x * 256 + threadIdx.x) << 2;
  if (idx >= n) return;
  float4 v = *(const float4*)(in + idx);
  short4 h;
  h.x = f2bf(gelu_f(v.x));
  h.y = f2bf(gelu_f(v.y));
  h.z = f2bf(gelu_f(v.z));
  h.w = f2bf(gelu_f(v.w));
  *(short4*)(oh + idx) = h;
}

// ---------------- pack attention keep-mask into bits ----------------
__global__ __launch_bounds__(256) void maskpack_kernel(const float* __restrict__ mlog,
    unsigned* __restrict__ bits) {
  int idx = blockIdx.x * 256 + threadIdx.x;
  if (idx >= NQ * NWRD) return;
  int q = idx / NWRD, w = idx - q * NWRD;
  unsigned word = 0u;
  int c0 = w * 32;
#pragma unroll
  for (int b = 0; b < 32; ++b) {
    int c = c0 + b;
    unsigned keep;
    if (c < NQ + PFX) keep = 1u;
    else if (c < NT) keep = (mlog[(size_t)q * NPATCH + (c - NQ - PFX)] > 0.f) ? 1u : 0u;
    else keep = 0u;
    word |= keep << b;
  }
  bits[idx] = word;
}

// ---------------- flash attention, MFMA, double-buffered K/V (1 barrier/tile) ----------------
// QK^T 3-term (Qh·Kh + Qh·Kl + Ql·Kh); PV 1-term (Ph·Vh).
// K/V in 2x [64][64]-short LDS tiles with 8-short-chunk XOR swizzle.
// Iteration t: compute(buf) interleaves with writeKV(buf^1, t+1); loads for t+2
// issued after; ONE barrier. Buf reuse is safe: readers of buf finish before the
// end-of-t barrier; buf is rewritten only in iteration t+1 after that barrier.
__global__ __launch_bounds__(256, 2) void fattn_kernel(
    const short* __restrict__ qh, const short* __restrict__ ql,
    const unsigned* __restrict__ bits,
    short* __restrict__ ao_h, short* __restrict__ ao_l) {
  const int bid = blockIdx.x;
  const int h = bid & 15;
  const int q0 = (bid >> 4) * 64;
  const int tid = threadIdx.x;
  const int lane = tid & 63;
  const int w = tid >> 6;
  const int lg = lane >> 4;
  const int lc = lane & 15;

  __shared__ __align__(16) short Kh[2 * 64 * 64], Kl[2 * 64 * 64];
  __shared__ __align__(16) short Vt[2 * 64 * 64];   // V^T hi-only: row d, col kv
  __shared__ __align__(16) short Pp[4][16 * 64];    // per-wave P hi (wave-private)
  __shared__ float fb[4][16];

  // Q fragments: direct bf16 hi/lo loads
  s16x8 qfh[2], qfl[2];
  {
    int gq = min(q0 + (w << 4) + lc, NT - 1);
    const size_t base = (size_t)gq * 3072 + h * 64;
#pragma unroll
    for (int ks = 0; ks < 2; ++ks) {
      qfh[ks] = *(const s16x8*)(qh + base + ks * 32 + (lg << 3));
      qfl[ks] = *(const s16x8*)(ql + base + ks * 32 + (lg << 3));
    }
  }

  const int krow = tid >> 3, kchk = tid & 7;
  const int vrow = tid >> 2, vchk = tid & 3;
  uint4 pkh[2], pkl[2], pvh[2];
  auto loadKV = [&](int kt) {
#pragma unroll
    for (int ii = 0; ii < 2; ++ii) {
      int gk = kt * 64 + krow + (ii << 5);
      if (gk < NT) {
        size_t b = (size_t)gk * 3072 + 1024 + h * 64 + (kchk << 3);
        pkh[ii] = *(const uint4*)(qh + b);
        pkl[ii] = *(const uint4*)(ql + b);
      } else {
        pkh[ii] = make_uint4(0, 0, 0, 0);
        pkl[ii] = make_uint4(0, 0, 0, 0);
      }
      int gv = kt * 64 + vrow;
      int vc = vchk + (ii << 2);
      if (gv < NT) {
        pvh[ii] = *(const uint4*)(qh + (size_t)gv * 3072 + 2048 + h * 64 + (vc << 3));
      } else {
        pvh[ii] = make_uint4(0, 0, 0, 0);
      }
    }
  };
  auto writeKV = [&](int buf) {
    const int bo = buf << 12;  // 64*64
#pragma unroll
    for (int ii = 0; ii < 2; ++ii) {
      int row = krow + (ii << 5);
      int off = bo + (row << 6) + ((kchk ^ (row & 7)) << 3);
      *(uint4*)&Kh[off] = pkh[ii];
      *(uint4*)&Kl[off] = pkl[ii];
      int vc = vchk + (ii << 2);
      const short* vs = (const short*)&pvh[ii];
#pragma unroll
      for (int jj = 0; jj < 8; ++jj) {
        int d = (vc << 3) + jj;
        Vt[bo + (d << 6) + (((vrow >> 3) ^ (d & 7)) << 3) + (vrow & 7)] = vs[jj];
      }
    }
  };

  float rm_r[4], rl_r[4];
#pragma unroll
  for (int r = 0; r < 4; ++r) { rm_r[r] = -3.0e38f; rl_r[r] = 0.f; }
  f32x4 o_acc[4];
  {
    f32x4 zf = {0.f, 0.f, 0.f, 0.f};
#pragma unroll
    for (int nd = 0; nd < 4; ++nd) o_acc[nd] = zf;
  }

  // ---- pipeline prologue: stage tile 0, issue loads for tile 1 ----
  loadKV(0);
  writeKV(0);
  __syncthreads();
  loadKV(1);

  for (int kt = 0; kt < NKT; ++kt) {
    const int cb = (kt & 1) << 12;

    // ---- QK^T (3-term) on buffer cb ----
    f32x4 sc[4];
    {
      f32x4 zf = {0.f, 0.f, 0.f, 0.f};
#pragma unroll
      for (int ni = 0; ni < 4; ++ni) sc[ni] = zf;
    }
    __builtin_amdgcn_s_setprio(1);
#pragma unroll
    for (int ni = 0; ni < 4; ++ni) {
#pragma unroll
      for (int ks = 0; ks < 2; ++ks) {
        int row = (ni << 4) + lc;
        int ch = ((ks << 2) + lg) ^ (row & 7);
        s16x8 kh = *(const s16x8*)&Kh[cb + (row << 6) + (ch << 3)];
        s16x8 kl = *(const s16x8*)&Kl[cb + (row << 6) + (ch << 3)];
        sc[ni] = __builtin_amdgcn_mfma_f32_16x16x32_bf16(qfh[ks], kh, sc[ni], 0, 0, 0);
        sc[ni] = __builtin_amdgcn_mfma_f32_16x16x32_bf16(qfh[ks], kl, sc[ni], 0, 0, 0);
        sc[ni] = __builtin_amdgcn_mfma_f32_16x16x32_bf16(qfl[ks], kh, sc[ni], 0, 0, 0);
      }
    }
    __builtin_amdgcn_s_setprio(0);

    // ---- scale + mask + OOB ----
    unsigned wr0[4], wr1[4];
#pragma unroll
    for (int r = 0; r < 4; ++r) {
      int gq = q0 + (w << 4) + (lg << 2) + r;
      wr0[r] = 0xFFFFFFFFu; wr1[r] = 0xFFFFFFFFu;
      if (gq < NQ) {
        wr0[r] = bits[gq * NWRD + (kt << 1)];
        wr1[r] = ((kt << 1) + 1 < NWRD) ? bits[gq * NWRD + (kt << 1) + 1] : 0u;
      }
    }
    const int kvb = kt << 6;
#pragma unroll
    for (int ni = 0; ni < 4; ++ni) {
      int kv = kvb + (ni << 4) + lc;
      unsigned bitpos = ((ni & 1) << 4) + lc;
#pragma unroll
      for (int r = 0; r < 4; ++r) {
        float sv = sc[ni][r] * 0.125f;
        unsigned wd = (ni < 2) ? wr0[r] : wr1[r];
        if (!((wd >> bitpos) & 1u)) sv -= 1e9f;
        sc[ni][r] = (kv < NT) ? sv : -3.0e38f;
      }
    }

    // ---- online softmax ----
    float fr[4];
#pragma unroll
    for (int r = 0; r < 4; ++r) {
      float tm = fmaxf(fmaxf(sc[0][r], sc[1][r]), fmaxf(sc[2][r], sc[3][r]));
#pragma unroll
      for (int m2 = 1; m2 < 16; m2 <<= 1) tm = fmaxf(tm, __shfl_xor(tm, m2, 64));
      float mnew = fmaxf(rm_r[r], tm);
      float f = __expf(rm_r[r] - mnew);
      float ps = 0.f;
#pragma unroll
      for (int ni = 0; ni < 4; ++ni) {
        float e = __expf(sc[ni][r] - mnew);
        sc[ni][r] = e;
        ps += e;
      }
#pragma unroll
      for (int m2 = 1; m2 < 16; m2 <<= 1) ps += __shfl_xor(ps, m2, 64);
      rm_r[r] = mnew;
      rl_r[r] = rl_r[r] * f + ps;
      fr[r] = f;
    }

    // ---- P (hi only) -> per-wave LDS tile (wave-private, no barrier) ----
    short* P = Pp[w];
#pragma unroll
    for (int ni = 0; ni < 4; ++ni) {
#pragma unroll
      for (int r = 0; r < 4; ++r) {
        int qq = (lg << 2) + r;
        int col = (ni << 4) + lc;
        P[(qq << 6) + (((col >> 3) ^ (qq & 7)) << 3) + (col & 7)] = f2bf(sc[ni][r]);
      }
    }
    if (lc == 0) {
#pragma unroll
      for (int r = 0; r < 4; ++r) fb[w][(lg << 2) + r] = fr[r];
    }
    float fq = fb[w][lc];
#pragma unroll
    for (int nd = 0; nd < 4; ++nd)
#pragma unroll
      for (int r = 0; r < 4; ++r) o_acc[nd][r] *= fq;

    // ---- PV: O^T = V^T_h @ P^T_h ----
    s16x8 pfrag[2];
#pragma unroll
    for (int ks = 0; ks < 2; ++ks)
      pfrag[ks] = *(const s16x8*)&P[(lc << 6) + ((((ks << 2) + lg) ^ (lc & 7)) << 3)];
    __builtin_amdgcn_s_setprio(1);
#pragma unroll
    for (int nd = 0; nd < 4; ++nd) {
      int row = (nd << 4) + lc;
#pragma unroll
      for (int ks = 0; ks < 2; ++ks) {
        s16x8 vh = *(const s16x8*)&Vt[cb + (row << 6) + ((((ks << 2) + lg) ^ (lc & 7)) << 3)];
        o_acc[nd] = __builtin_amdgcn_mfma_f32_16x16x32_bf16(vh, pfrag[ks], o_acc[nd], 0, 0, 0);
      }
    }
    __builtin_amdgcn_s_setprio(0);

    // ---- stage tile kt+1 into other buffer; issue loads for kt+2; ONE barrier ----
    if (kt + 1 < NKT) {
      writeKV((kt + 1) & 1);
      if (kt + 2 < NKT) loadKV(kt + 2);
      __syncthreads();
    }
  }

  // ---- epilogue: normalize + store ----
  if (lc == 0) {
#pragma unroll
    for (int r = 0; r < 4; ++r) fb[w][(lg << 2) + r] = rl_r[r];
  }
  float inv = 1.0f / fb[w][lc];
  int gq = q0 + (w << 4) + lc;
  if (gq < NT) {
#pragma unroll
    for (int nd = 0; nd < 4; ++nd) {
      short hh[4], ll[4];
#pragma unroll
      for (int r = 0; r < 4; ++r) {
        float v = o_acc[nd][r] * inv;
        hh[r] = f2bf(v);
        ll[r] = f2bf(v - bf2f(hh[r]));
      }
      size_t o = (size_t)gq * DM + h * 64 + (nd << 4) + (lg << 2);
      *(short4*)(ao_h + o) = make_short4(hh[0], hh[1], hh[2], hh[3]);
      *(short4*)(ao_l + o) = make_short4(ll[0], ll[1], ll[2], ll[3]);
    }
  }
}

// ---------------- residual with layer-scale: x += ls * y ----------------
__global__ __launch_bounds__(256) void resid_kernel(float* __restrict__ x,
    const float* __restrict__ y, const float* __restrict__ ls) {
  int idx = blockIdx.x * 256 + threadIdx.x;
  if (idx >= NT * DM) return;
  int d = idx & (DM - 1);
  x[idx] = fmaf(ls[d], y[idx], x[idx]);
}

extern "C" void kernel_launch(void* const* d_in, const int* in_sizes, int n_in,
                              void* d_out, int out_size, void* d_ws, size_t ws_size,
                              hipStream_t stream) {
  const float* x_tokens = (const float*)d_in[0];
  const float* q_weight = (const float*)d_in[1];
  const float* norm_g   = (const float*)d_in[2];
  const float* norm_b   = (const float*)d_in[3];
  const float* class_W  = (const float*)d_in[4];
  const float* class_b  = (const float*)d_in[5];
  const float* mask_W1  = (const float*)d_in[6];
  const float* mask_b1  = (const float*)d_in[7];
  const float* mask_W2  = (const float*)d_in[8];
  const float* mask_b2  = (const float*)d_in[9];
  const float* mask_W3  = (const float*)d_in[10];
  const float* mask_b3  = (const float*)d_in[11];
  const float* ln1_g    = (const float*)d_in[12];
  const float* ln1_b    = (const float*)d_in[13];
  const float* ln2_g    = (const float*)d_in[14];
  const float* ln2_b    = (const float*)d_in[15];
  const float* qkv_W    = (const float*)d_in[16];
  const float* qkv_b    = (const float*)d_in[17];
  const float* proj_W   = (const float*)d_in[18];
  const float* proj_b   = (const float*)d_in[19];
  const float* ls1      = (const float*)d_in[20];
  const float* ls2      = (const float*)d_in[21];
  const float* fc1_W    = (const float*)d_in[22];
  const float* fc1_b    = (const float*)d_in[23];
  const float* fc2_W    = (const float*)d_in[24];
  const float* fc2_b    = (const float*)d_in[25];

  float* out = (float*)d_out;

  // ---- workspace carve: ~59.2 MB total (< 60.86 proven) ----
  char* p = (char*)d_ws;
  auto alloc = [&](size_t bytes) {
    char* r = p;
    p += (bytes + 255) & ~(size_t)255;
    return r;
  };
  float* x     = (float*)alloc((size_t)NT * DM * 4);       // 7.39
  short* lnb_h = (short*)alloc((size_t)NT * DM * 2);       // 3.70 } fc2o overlays
  short* lnb_l = (short*)alloc((size_t)NT * DM * 2);       // 3.70 }
  char*  A1    = alloc((size_t)NT * 4 * DM * 4);           // 29.57: qkv h/l | fc1acc | predict
  char*  A2    = alloc((size_t)NT * 4 * DM * 2);           // 14.78: ao h/l + projo | g1h
  unsigned* bias_bits = (unsigned*)alloc((size_t)NQ * NWRD * 4);

  short* qkvh   = (short*)A1;                        // NT*3DM shorts
  short* qkvl   = qkvh + (size_t)NT * 3 * DM;        // NT*3DM shorts
  float* fc1acc = (float*)A1;                        // NT*4DM fp32
  short* f1_h = (short*)A1;                          // predict scratch (first 2.46 MB)
  short* f1_l = f1_h + (size_t)NQ * DM;
  short* f2_h = f1_l + (size_t)NQ * DM;
  short* f2_l = f2_h + (size_t)NQ * DM;
  short* f3_h = f2_l + (size_t)NQ * DM;
  short* f3_l = f3_h + (size_t)NQ * DM;
  float* pbuf = (float*)(A1 + ((size_t)4 << 20));    // partials at A1+4MB (<=6.55MB)
  short* aoh   = (short*)A2;                         // NT*DM
  short* aol   = aoh + (size_t)NT * DM;
  float* projo = (float*)(A2 + (size_t)NT * DM * 4); // NT*DM fp32 (upper half of A2)
  short* g1h   = (short*)A2;                         // NT*4DM shorts (full A2)
  float* fc2o  = (float*)lnb_h;                      // NT*DM fp32 (lnb region, dead then)

  const int ELEM_GRID = (NT * DM + 255) / 256;
  auto g128 = [](int M, int Nc, int ks) { return dim3((Nc + 127) / 128, (M + 127) / 128, ks); };
  auto g64  = [](int M, int Nc, int ks) { return dim3((Nc + 127) / 128, (M + 63) / 64, ks); };
  auto rgrid = [](int n) { return dim3((n + 255) / 256); };

  concat_kernel<<<ELEM_GRID, 256, 0, stream>>>(q_weight, x_tokens, x);

  for (int i = 0; i <= NBLK; ++i) {
    // ---- predict head on shared-norm LN(x) ----
    ln_kernel<<<NT, 256, 0, stream>>>(x, norm_g, norm_b, lnb_h, lnb_l);
    float* mask_i = out + (size_t)i * NQ * NPATCH;
    float* cls_i  = out + (size_t)5 * NQ * NPATCH + (size_t)i * NQ * NCLS;
    mgemm_kernel<1, 0, 1, 0, 3, 8><<<g64(NQ, DM, 8), 256, 0, stream>>>(
        lnb_h, lnb_l, mask_W1, nullptr, nullptr, mask_b1, pbuf, nullptr, nullptr, NQ, DM, DM);
    redsplit_kernel<1, 1><<<rgrid(NQ * DM), 256, 0, stream>>>(pbuf, nullptr, f1_h, f1_l, 8, NQ * DM);
    mgemm_kernel<1, 0, 1, 0, 3, 8><<<g64(NQ, DM, 8), 256, 0, stream>>>(
        f1_h, f1_l, mask_W2, nullptr, nullptr, mask_b2, pbuf, nullptr, nullptr, NQ, DM, DM);
    redsplit_kernel<1, 1><<<rgrid(NQ * DM), 256, 0, stream>>>(pbuf, nullptr, f2_h, f2_l, 8, NQ * DM);
    mgemm_kernel<1, 0, 1, 0, 3, 8><<<g64(NQ, DM, 8), 256, 0, stream>>>(
        f2_h, f2_l, mask_W3, nullptr, nullptr, mask_b3, pbuf, nullptr, nullptr, NQ, DM, DM);
    redsplit_kernel<0, 1><<<rgrid(NQ * DM), 256, 0, stream>>>(pbuf, nullptr, f3_h, f3_l, 8, NQ * DM);
    mgemm_kernel<1, 1, 1, 0, 3, 4><<<g64(NQ, NPATCH, 4), 256, 0, stream>>>(
        f3_h, f3_l, nullptr, lnb_h + (size_t)(NQ + PFX) * DM, lnb_l + (size_t)(NQ + PFX) * DM,
        nullptr, pbuf, nullptr, nullptr, NQ, NPATCH, DM);
    redsplit_kernel<0, 0><<<rgrid(NQ * NPATCH), 256, 0, stream>>>(
        pbuf, mask_i, nullptr, nullptr, 4, NQ * NPATCH);
    mgemm_kernel<1, 0, 1, 0, 3, 8><<<g64(NQ, NCLS, 8), 256, 0, stream>>>(
        lnb_h, lnb_l, class_W, nullptr, nullptr, class_b, pbuf, nullptr, nullptr, NQ, NCLS, DM);
    redsplit_kernel<0, 0><<<rgrid(NQ * NCLS), 256, 0, stream>>>(
        pbuf, cls_i, nullptr, nullptr, 8, NQ * NCLS);
    if (i == NBLK) break;

    // ---- transformer block i ----
    ln_kernel<<<NT, 256, 0, stream>>>(x, ln1_g + i * DM, ln1_b + i * DM, lnb_h, lnb_l);
    mgemm_kernel<0, 0, 1, 0, 0, 1><<<g128(NT, 3 * DM, 1), 256, 0, stream>>>(
        lnb_h, lnb_l, qkv_W + (size_t)i * DM * 3 * DM, nullptr, nullptr,
        qkv_b + i * 3 * DM, nullptr, qkvh, qkvl, NT, 3 * DM, DM);
    maskpack_kernel<<<(NQ * NWRD + 255) / 256, 256, 0, stream>>>(mask_i, bias_bits);
    fattn_kernel<<<NKT * NHEAD, 256, 0, stream>>>(qkvh, qkvl, bias_bits, aoh, aol);
    hipMemsetAsync(projo, 0, (size_t)NT * DM * 4, stream);
    mgemm_kernel<1, 0, 1, 0, 2, 4><<<g64(NT, DM, 4), 256, 0, stream>>>(
        aoh, aol, proj_W + (size_t)i * DM * DM, nullptr, nullptr,
        proj_b + i * DM, projo, nullptr, nullptr, NT, DM, DM);
    resid_kernel<<<ELEM_GRID, 256, 0, stream>>>(x, projo, ls1 + i * DM);
    ln_kernel<<<NT, 256, 0, stream>>>(x, ln2_g + i * DM, ln2_b + i * DM, lnb_h, lnb_l);
    hipMemsetAsync(fc1acc, 0, (size_t)NT * 4 * DM * 4, stream);
    mgemm_kernel<0, 0, 1, 0, 2, 2><<<g128(NT, 4 * DM, 2), 256, 0, stream>>>(
        lnb_h, lnb_l, fc1_W + (size_t)i * DM * 4 * DM, nullptr, nullptr,
        fc1_b + i * 4 * DM, fc1acc, nullptr, nullptr, NT, 4 * DM, DM);
    gelusplit_kernel<<<rgrid(NT * DM), 256, 0, stream>>>(fc1acc, g1h, NT * 4 * DM);
    hipMemsetAsync(fc2o, 0, (size_t)NT * DM * 4, stream);
    mgemm_kernel<1, 0, 0, 0, 2, 4><<<g64(NT, DM, 4), 256, 0, stream>>>(
        g1h, nullptr, fc2_W + (size_t)i * 4 * DM * DM, nullptr, nullptr,
        fc2_b + i * DM, fc2o, nullptr, nullptr, NT, DM, 4 * DM);
    resid_kernel<<<ELEM_GRID, 256, 0, stream>>>(x, fc2o, ls2 + i * DM);
  }
}

// Round 14
// 1701.524 us; speedup vs baseline: 1.3970x; 1.1446x over previous
//
#include <hip/hip_runtime.h>
#include <hip/hip_bf16.h>

#define NQ 200
#define PFX 5
#define NPATCH 1600
#define NT 1805
#define DM 1024
#define NHEAD 16
#define DHEAD 64
#define NBLK 4
#define NCLS 151
#define NKT 29     // ceil(1805/64) kv tiles
#define NWRD 57    // ceil(1805/32) mask words per query row

typedef short s16x8 __attribute__((ext_vector_type(8)));
typedef float f32x4 __attribute__((ext_vector_type(4)));

__device__ __forceinline__ float gelu_f(float x) {
  return 0.5f * x * (1.0f + erff(x * 0.7071067811865476f));
}
__device__ __forceinline__ short f2bf(float x) {
  __hip_bfloat16 h = __float2bfloat16(x);
  return *reinterpret_cast<short*>(&h);
}
__device__ __forceinline__ float bf2f(short s) {
  __hip_bfloat16 h;
  *reinterpret_cast<short*>(&h) = s;
  return __bfloat162float(h);
}
// async 16B global->LDS (width literal 16). LDS dest must be wave-uniform base.
__device__ __forceinline__ void glds16(const void* g, void* l) {
  __builtin_amdgcn_global_load_lds(
      (const __attribute__((address_space(1))) void*)g,
      (__attribute__((address_space(3))) void*)l, 16, 0, 0);
}

// ---------------- concat: x = [q_weight ; x_tokens] ----------------
__global__ __launch_bounds__(256) void concat_kernel(const float* __restrict__ qw,
    const float* __restrict__ xt, float* __restrict__ x) {
  int idx = blockIdx.x * 256 + threadIdx.x;
  if (idx >= NT * DM) return;
  int n = idx >> 10;
  x[idx] = (n < NQ) ? qw[idx] : xt[idx - NQ * DM];
}

// ---------------- LayerNorm -> bf16 hi/lo ----------------
__global__ __launch_bounds__(256) void ln_kernel(const float* __restrict__ in,
    const float* __restrict__ g, const float* __restrict__ b,
    short* __restrict__ oh, short* __restrict__ ol) {
  const int row = blockIdx.x;
  const int tid = threadIdx.x;
  const float* x = in + (size_t)row * DM;
  float v[4];
#pragma unroll
  for (int i = 0; i < 4; ++i) v[i] = x[tid + (i << 8)];
  float s = v[0] + v[1] + v[2] + v[3];
  __shared__ float red[4];
  __shared__ float red2[4];
#pragma unroll
  for (int off = 32; off; off >>= 1) s += __shfl_down(s, off, 64);
  if ((tid & 63) == 0) red[tid >> 6] = s;
  __syncthreads();
  float mean = (red[0] + red[1] + red[2] + red[3]) * (1.0f / DM);
  float sq = 0.f;
#pragma unroll
  for (int i = 0; i < 4; ++i) { float d = v[i] - mean; sq += d * d; }
#pragma unroll
  for (int off = 32; off; off >>= 1) sq += __shfl_down(sq, off, 64);
  if ((tid & 63) == 0) red2[tid >> 6] = sq;
  __syncthreads();
  float var = (red2[0] + red2[1] + red2[2] + red2[3]) * (1.0f / DM);
  float inv = 1.0f / sqrtf(var + 1e-6f);
#pragma unroll
  for (int i = 0; i < 4; ++i) {
    int d = tid + (i << 8);
    float y = (v[i] - mean) * inv * g[d] + b[d];
    short hh = f2bf(y);
    oh[(size_t)row * DM + d] = hh;
    ol[(size_t)row * DM + d] = f2bf(y - bf2f(hh));
  }
}

// ---------------- bf16x3 MFMA GEMM: dbuf LDS + split-K + fused epilogues ----------------
// OMODE: 0 bf16 h/l out (+ACT); 1 fp32 out (+ACT); 2 atomicAdd fp32 (bias z==0);
//        3 partial fp32 at Cf + z*M*N (bias z==0);
//        4 bf16 HI-only out (+ACT);
//        5 fused residual: atomicAdd(Cf[o], lsv[col]*(v+bias)) (bias z==0).
template <int BM64, int BSRC, int ALO, int ACT, int OMODE, int KS>
__global__ __launch_bounds__(256) void mgemm_kernel(
    const short* __restrict__ Ah, const short* __restrict__ Al,
    const float* __restrict__ Wf,
    const short* __restrict__ Bh, const short* __restrict__ Bl,
    const float* __restrict__ bias, const float* __restrict__ lsv,
    float* __restrict__ Cf, short* __restrict__ Ch, short* __restrict__ Cl,
    int M, int N, int K) {
  constexpr int BM = BM64 ? 64 : 128;
  constexpr int AT = BM64 ? 2 : 4;
  constexpr int AISS = BM64 ? 1 : 2;
  __shared__ __align__(16) short sAh[2 * BM * 32];
  __shared__ __align__(16) short sAl[ALO ? 2 * BM * 32 : 8];
  __shared__ __align__(16) short sBh[2 * 128 * 32], sBl[2 * 128 * 32];
  const int tid = threadIdx.x;
  const int lane = tid & 63;
  const int w = tid >> 6;
  const int bm = blockIdx.y * BM;
  const int bn = blockIdx.x << 7;
  const int z = (KS > 1) ? blockIdx.z : 0;
  const int KL = K / KS;
  const int kbase = z * KL;

  f32x4 acc[AT][4];
  {
    f32x4 zf = {0.f, 0.f, 0.f, 0.f};
#pragma unroll
    for (int mi = 0; mi < AT; ++mi)
#pragma unroll
      for (int ni = 0; ni < 4; ++ni) acc[mi][ni] = zf;
  }

  auto issueA = [&](int buf, int k0) {
#pragma unroll
    for (int i = 0; i < AISS; ++i) {
      int br = (BM64 ? (w << 4) : (w << 5) + (i << 4));
      int r = br + (lane >> 2);
      int cg = (lane & 3) ^ ((r >> 1) & 3);
      size_t go = (size_t)min(bm + r, M - 1) * K + kbase + k0 + (cg << 3);
      glds16(Ah + go, &sAh[(buf * BM + br) * 32]);
      if (ALO) glds16(Al + go, &sAl[(buf * BM + br) * 32]);
    }
  };
  auto issueB1 = [&](int buf, int k0) {
#pragma unroll
    for (int i = 0; i < 2; ++i) {
      int br = (w << 5) + (i << 4);
      int r = br + (lane >> 2);
      int cg = (lane & 3) ^ ((r >> 1) & 3);
      size_t go = (size_t)min(bn + r, N - 1) * K + kbase + k0 + (cg << 3);
      glds16(Bh + go, &sBh[(buf * 128 + br) * 32]);
      glds16(Bl + go, &sBl[(buf * 128 + br) * 32]);
    }
  };
  float wv[2][8];
  auto loadB0 = [&](int k0) {
#pragma unroll
    for (int p = 0; p < 2; ++p) {
      int n = tid & 127;
      int c8 = (tid >> 7) + (p << 1);
      const float* Wp = Wf + (size_t)(kbase + k0 + (c8 << 3)) * N + min(bn + n, N - 1);
#pragma unroll
      for (int j = 0; j < 8; ++j) wv[p][j] = Wp[(size_t)j * N];
    }
  };
  auto writeB0 = [&](int buf) {
#pragma unroll
    for (int p = 0; p < 2; ++p) {
      int n = tid & 127;
      int c8 = (tid >> 7) + (p << 1);
      int cp = c8 ^ ((n >> 1) & 3);
      union { uint4 u; short e[8]; } H, L;
#pragma unroll
      for (int j = 0; j < 8; ++j) {
        short hh = f2bf(wv[p][j]);
        H.e[j] = hh;
        L.e[j] = f2bf(wv[p][j] - bf2f(hh));
      }
      int off = (buf * 128 + n) * 32 + (cp << 3);
      *(uint4*)&sBh[off] = H.u;
      *(uint4*)&sBl[off] = L.u;
    }
  };

  issueA(0, 0);
  if (BSRC == 1) issueB1(0, 0);
  else { loadB0(0); writeB0(0); }
  __syncthreads();

  const int nt = KL >> 5;
  int cur = 0;
  const int ar = lane & 15;
  const int kc = lane >> 4;
  const int wmr = BM64 ? ((w >> 1) << 5) : ((w >> 1) << 6);
  const int wnr = (w & 1) << 6;

  for (int t = 0; t < nt; ++t) {
    const bool more = (t + 1 < nt);
    if (more) {
      int k0n = (t + 1) << 5;
      issueA(cur ^ 1, k0n);
      if (BSRC == 1) issueB1(cur ^ 1, k0n);
      else loadB0(k0n);
    }
    s16x8 fah[AT], fal[AT], fbh[4], fbl[4];
#pragma unroll
    for (int t2 = 0; t2 < AT; ++t2) {
      int r = wmr + (t2 << 4) + ar;
      int off = (cur * BM + r) * 32 + ((kc ^ ((r >> 1) & 3)) << 3);
      fah[t2] = *(const s16x8*)&sAh[off];
      if (ALO) fal[t2] = *(const s16x8*)&sAl[off];
    }
#pragma unroll
    for (int t2 = 0; t2 < 4; ++t2) {
      int r = wnr + (t2 << 4) + ar;
      int off = (cur * 128 + r) * 32 + ((kc ^ ((r >> 1) & 3)) << 3);
      fbh[t2] = *(const s16x8*)&sBh[off];
      fbl[t2] = *(const s16x8*)&sBl[off];
    }
#pragma unroll
    for (int mi = 0; mi < AT; ++mi)
#pragma unroll
      for (int ni = 0; ni < 4; ++ni) {
        acc[mi][ni] = __builtin_amdgcn_mfma_f32_16x16x32_bf16(fah[mi], fbh[ni], acc[mi][ni], 0, 0, 0);
        acc[mi][ni] = __builtin_amdgcn_mfma_f32_16x16x32_bf16(fah[mi], fbl[ni], acc[mi][ni], 0, 0, 0);
        if (ALO)
          acc[mi][ni] = __builtin_amdgcn_mfma_f32_16x16x32_bf16(fal[mi], fbh[ni], acc[mi][ni], 0, 0, 0);
      }
    if (more) {
      if (BSRC == 0) writeB0(cur ^ 1);
      __syncthreads();
      cur ^= 1;
    }
  }

  const int erow = bm + wmr + ((lane >> 4) << 2);
  const int ecol = bn + wnr + (lane & 15);
  float bv[4], lv[4];
#pragma unroll
  for (int ni = 0; ni < 4; ++ni) {
    int col = ecol + ni * 16;
    float b0 = (bias != nullptr && col < N) ? bias[col] : 0.f;
    bv[ni] = (KS > 1 && z != 0) ? 0.f : b0;
    lv[ni] = (OMODE == 5 && col < N) ? lsv[col] : 0.f;
  }
#pragma unroll
  for (int mi = 0; mi < AT; ++mi) {
#pragma unroll
    for (int rr = 0; rr < 4; ++rr) {
      int row = erow + mi * 16 + rr;
      if (row >= M) continue;
#pragma unroll
      for (int ni = 0; ni < 4; ++ni) {
        int col = ecol + ni * 16;
        if (col >= N) continue;
        float v = acc[mi][ni][rr] + bv[ni];
        size_t o = (size_t)row * N + col;
        if (OMODE == 0) {
          if (ACT == 1) v = gelu_f(v);
          short hh = f2bf(v);
          Ch[o] = hh;
          Cl[o] = f2bf(v - bf2f(hh));
        } else if (OMODE == 1) {
          if (ACT == 1) v = gelu_f(v);
          Cf[o] = v;
        } else if (OMODE == 2) {
          atomicAdd(&Cf[o], v);
        } else if (OMODE == 3) {
          Cf[(size_t)z * M * N + o] = v;
        } else if (OMODE == 4) {
          if (ACT == 1) v = gelu_f(v);
          Ch[o] = f2bf(v);
        } else {  // OMODE == 5: fused layer-scale residual
          atomicAdd(&Cf[o], lv[ni] * v);
        }
      }
    }
  }
}

// ---------------- split-K partial reduce (+act, +bf16 hi/lo split) ----------------
template <int ACT, int WSPLIT>
__global__ __launch_bounds__(256) void redsplit_kernel(const float* __restrict__ pb,
    float* __restrict__ outf, short* __restrict__ oh, short* __restrict__ ol,
    int KSr, int MN) {
  int idx = blockIdx.x * 256 + threadIdx.x;
  if (idx >= MN) return;
  float s = 0.f;
  for (int zz = 0; zz < KSr; ++zz) s += pb[(size_t)zz * MN + idx];
  if (ACT == 1) s = gelu_f(s);
  if (WSPLIT) {
    short hh = f2bf(s);
    oh[idx] = hh;
    ol[idx] = f2bf(s - bf2f(hh));
  } else {
    outf[idx] = s;
  }
}

// ---------------- pack attention keep-mask into bits ----------------
__global__ __launch_bounds__(256) void maskpack_kernel(const float* __restrict__ mlog,
    unsigned* __restrict__ bits) {
  int idx = blockIdx.x * 256 + threadIdx.x;
  if (idx >= NQ * NWRD) return;
  int q = idx / NWRD, w = idx - q * NWRD;
  unsigned word = 0u;
  int c0 = w * 32;
#pragma unroll
  for (int b = 0; b < 32; ++b) {
    int c = c0 + b;
    unsigned keep;
    if (c < NQ + PFX) keep = 1u;
    else if (c < NT) keep = (mlog[(size_t)q * NPATCH + (c - NQ - PFX)] > 0.f) ? 1u : 0u;
    else keep = 0u;
    word |= keep << b;
  }
  bits[idx] = word;
}

// ---------------- flash attention, MFMA, double-buffered K/V (1 barrier/tile) ----------------
__global__ __launch_bounds__(256, 2) void fattn_kernel(
    const short* __restrict__ qh, const short* __restrict__ ql,
    const unsigned* __restrict__ bits,
    short* __restrict__ ao_h, short* __restrict__ ao_l) {
  const int bid = blockIdx.x;
  const int h = bid & 15;
  const int q0 = (bid >> 4) * 64;
  const int tid = threadIdx.x;
  const int lane = tid & 63;
  const int w = tid >> 6;
  const int lg = lane >> 4;
  const int lc = lane & 15;

  __shared__ __align__(16) short Kh[2 * 64 * 64], Kl[2 * 64 * 64];
  __shared__ __align__(16) short Vt[2 * 64 * 64];
  __shared__ __align__(16) short Pp[4][16 * 64];
  __shared__ float fb[4][16];

  s16x8 qfh[2], qfl[2];
  {
    int gq = min(q0 + (w << 4) + lc, NT - 1);
    const size_t base = (size_t)gq * 3072 + h * 64;
#pragma unroll
    for (int ks = 0; ks < 2; ++ks) {
      qfh[ks] = *(const s16x8*)(qh + base + ks * 32 + (lg << 3));
      qfl[ks] = *(const s16x8*)(ql + base + ks * 32 + (lg << 3));
    }
  }

  const int krow = tid >> 3, kchk = tid & 7;
  const int vrow = tid >> 2, vchk = tid & 3;
  uint4 pkh[2], pkl[2], pvh[2];
  auto loadKV = [&](int kt) {
#pragma unroll
    for (int ii = 0; ii < 2; ++ii) {
      int gk = kt * 64 + krow + (ii << 5);
      if (gk < NT) {
        size_t b = (size_t)gk * 3072 + 1024 + h * 64 + (kchk << 3);
        pkh[ii] = *(const uint4*)(qh + b);
        pkl[ii] = *(const uint4*)(ql + b);
      } else {
        pkh[ii] = make_uint4(0, 0, 0, 0);
        pkl[ii] = make_uint4(0, 0, 0, 0);
      }
      int gv = kt * 64 + vrow;
      int vc = vchk + (ii << 2);
      if (gv < NT) {
        pvh[ii] = *(const uint4*)(qh + (size_t)gv * 3072 + 2048 + h * 64 + (vc << 3));
      } else {
        pvh[ii] = make_uint4(0, 0, 0, 0);
      }
    }
  };
  auto writeKV = [&](int buf) {
    const int bo = buf << 12;
#pragma unroll
    for (int ii = 0; ii < 2; ++ii) {
      int row = krow + (ii << 5);
      int off = bo + (row << 6) + ((kchk ^ (row & 7)) << 3);
      *(uint4*)&Kh[off] = pkh[ii];
      *(uint4*)&Kl[off] = pkl[ii];
      int vc = vchk + (ii << 2);
      const short* vs = (const short*)&pvh[ii];
#pragma unroll
      for (int jj = 0; jj < 8; ++jj) {
        int d = (vc << 3) + jj;
        Vt[bo + (d << 6) + (((vrow >> 3) ^ (d & 7)) << 3) + (vrow & 7)] = vs[jj];
      }
    }
  };

  float rm_r[4], rl_r[4];
#pragma unroll
  for (int r = 0; r < 4; ++r) { rm_r[r] = -3.0e38f; rl_r[r] = 0.f; }
  f32x4 o_acc[4];
  {
    f32x4 zf = {0.f, 0.f, 0.f, 0.f};
#pragma unroll
    for (int nd = 0; nd < 4; ++nd) o_acc[nd] = zf;
  }

  loadKV(0);
  writeKV(0);
  __syncthreads();
  loadKV(1);

  for (int kt = 0; kt < NKT; ++kt) {
    const int cb = (kt & 1) << 12;

    f32x4 sc[4];
    {
      f32x4 zf = {0.f, 0.f, 0.f, 0.f};
#pragma unroll
      for (int ni = 0; ni < 4; ++ni) sc[ni] = zf;
    }
    __builtin_amdgcn_s_setprio(1);
#pragma unroll
    for (int ni = 0; ni < 4; ++ni) {
#pragma unroll
      for (int ks = 0; ks < 2; ++ks) {
        int row = (ni << 4) + lc;
        int ch = ((ks << 2) + lg) ^ (row & 7);
        s16x8 kh = *(const s16x8*)&Kh[cb + (row << 6) + (ch << 3)];
        s16x8 kl = *(const s16x8*)&Kl[cb + (row << 6) + (ch << 3)];
        sc[ni] = __builtin_amdgcn_mfma_f32_16x16x32_bf16(qfh[ks], kh, sc[ni], 0, 0, 0);
        sc[ni] = __builtin_amdgcn_mfma_f32_16x16x32_bf16(qfh[ks], kl, sc[ni], 0, 0, 0);
        sc[ni] = __builtin_amdgcn_mfma_f32_16x16x32_bf16(qfl[ks], kh, sc[ni], 0, 0, 0);
      }
    }
    __builtin_amdgcn_s_setprio(0);

    unsigned wr0[4], wr1[4];
#pragma unroll
    for (int r = 0; r < 4; ++r) {
      int gq = q0 + (w << 4) + (lg << 2) + r;
      wr0[r] = 0xFFFFFFFFu; wr1[r] = 0xFFFFFFFFu;
      if (gq < NQ) {
        wr0[r] = bits[gq * NWRD + (kt << 1)];
        wr1[r] = ((kt << 1) + 1 < NWRD) ? bits[gq * NWRD + (kt << 1) + 1] : 0u;
      }
    }
    const int kvb = kt << 6;
#pragma unroll
    for (int ni = 0; ni < 4; ++ni) {
      int kv = kvb + (ni << 4) + lc;
      unsigned bitpos = ((ni & 1) << 4) + lc;
#pragma unroll
      for (int r = 0; r < 4; ++r) {
        float sv = sc[ni][r] * 0.125f;
        unsigned wd = (ni < 2) ? wr0[r] : wr1[r];
        if (!((wd >> bitpos) & 1u)) sv -= 1e9f;
        sc[ni][r] = (kv < NT) ? sv : -3.0e38f;
      }
    }

    float fr[4];
#pragma unroll
    for (int r = 0; r < 4; ++r) {
      float tm = fmaxf(fmaxf(sc[0][r], sc[1][r]), fmaxf(sc[2][r], sc[3][r]));
#pragma unroll
      for (int m2 = 1; m2 < 16; m2 <<= 1) tm = fmaxf(tm, __shfl_xor(tm, m2, 64));
      float mnew = fmaxf(rm_r[r], tm);
      float f = __expf(rm_r[r] - mnew);
      float ps = 0.f;
#pragma unroll
      for (int ni = 0; ni < 4; ++ni) {
        float e = __expf(sc[ni][r] - mnew);
        sc[ni][r] = e;
        ps += e;
      }
#pragma unroll
      for (int m2 = 1; m2 < 16; m2 <<= 1) ps += __shfl_xor(ps, m2, 64);
      rm_r[r] = mnew;
      rl_r[r] = rl_r[r] * f + ps;
      fr[r] = f;
    }

    short* P = Pp[w];
#pragma unroll
    for (int ni = 0; ni < 4; ++ni) {
#pragma unroll
      for (int r = 0; r < 4; ++r) {
        int qq = (lg << 2) + r;
        int col = (ni << 4) + lc;
        P[(qq << 6) + (((col >> 3) ^ (qq & 7)) << 3) + (col & 7)] = f2bf(sc[ni][r]);
      }
    }
    if (lc == 0) {
#pragma unroll
      for (int r = 0; r < 4; ++r) fb[w][(lg << 2) + r] = fr[r];
    }
    float fq = fb[w][lc];
#pragma unroll
    for (int nd = 0; nd < 4; ++nd)
#pragma unroll
      for (int r = 0; r < 4; ++r) o_acc[nd][r] *= fq;

    s16x8 pfrag[2];
#pragma unroll
    for (int ks = 0; ks < 2; ++ks)
      pfrag[ks] = *(const s16x8*)&P[(lc << 6) + ((((ks << 2) + lg) ^ (lc & 7)) << 3)];
    __builtin_amdgcn_s_setprio(1);
#pragma unroll
    for (int nd = 0; nd < 4; ++nd) {
      int row = (nd << 4) + lc;
#pragma unroll
      for (int ks = 0; ks < 2; ++ks) {
        s16x8 vh = *(const s16x8*)&Vt[cb + (row << 6) + ((((ks << 2) + lg) ^ (lc & 7)) << 3)];
        o_acc[nd] = __builtin_amdgcn_mfma_f32_16x16x32_bf16(vh, pfrag[ks], o_acc[nd], 0, 0, 0);
      }
    }
    __builtin_amdgcn_s_setprio(0);

    if (kt + 1 < NKT) {
      writeKV((kt + 1) & 1);
      if (kt + 2 < NKT) loadKV(kt + 2);
      __syncthreads();
    }
  }

  if (lc == 0) {
#pragma unroll
    for (int r = 0; r < 4; ++r) fb[w][(lg << 2) + r] = rl_r[r];
  }
  float inv = 1.0f / fb[w][lc];
  int gq = q0 + (w << 4) + lc;
  if (gq < NT) {
#pragma unroll
    for (int nd = 0; nd < 4; ++nd) {
      short hh[4], ll[4];
#pragma unroll
      for (int r = 0; r < 4; ++r) {
        float v = o_acc[nd][r] * inv;
        hh[r] = f2bf(v);
        ll[r] = f2bf(v - bf2f(hh[r]));
      }
      size_t o = (size_t)gq * DM + h * 64 + (nd << 4) + (lg << 2);
      *(short4*)(ao_h + o) = make_short4(hh[0], hh[1], hh[2], hh[3]);
      *(short4*)(ao_l + o) = make_short4(ll[0], ll[1], ll[2], ll[3]);
    }
  }
}

extern "C" void kernel_launch(void* const* d_in, const int* in_sizes, int n_in,
                              void* d_out, int out_size, void* d_ws, size_t ws_size,
                              hipStream_t stream) {
  const float* x_tokens = (const float*)d_in[0];
  const float* q_weight = (const float*)d_in[1];
  const float* norm_g   = (const float*)d_in[2];
  const float* norm_b   = (const float*)d_in[3];
  const float* class_W  = (const float*)d_in[4];
  const float* class_b  = (const float*)d_in[5];
  const float* mask_W1  = (const float*)d_in[6];
  const float* mask_b1  = (const float*)d_in[7];
  const float* mask_W2  = (const float*)d_in[8];
  const float* mask_b2  = (const float*)d_in[9];
  const float* mask_W3  = (const float*)d_in[10];
  const float* mask_b3  = (const float*)d_in[11];
  const float* ln1_g    = (const float*)d_in[12];
  const float* ln1_b    = (const float*)d_in[13];
  const float* ln2_g    = (const float*)d_in[14];
  const float* ln2_b    = (const float*)d_in[15];
  const float* qkv_W    = (const float*)d_in[16];
  const float* qkv_b    = (const float*)d_in[17];
  const float* proj_W   = (const float*)d_in[18];
  const float* proj_b   = (const float*)d_in[19];
  const float* ls1      = (const float*)d_in[20];
  const float* ls2      = (const float*)d_in[21];
  const float* fc1_W    = (const float*)d_in[22];
  const float* fc1_b    = (const float*)d_in[23];
  const float* fc2_W    = (const float*)d_in[24];
  const float* fc2_b    = (const float*)d_in[25];

  float* out = (float*)d_out;

  // ---- workspace carve (< 60.86 MB proven) ----
  char* p = (char*)d_ws;
  auto alloc = [&](size_t bytes) {
    char* r = p;
    p += (bytes + 255) & ~(size_t)255;
    return r;
  };
  float* x     = (float*)alloc((size_t)NT * DM * 4);       // 7.39
  short* lnb_h = (short*)alloc((size_t)NT * DM * 2);       // 3.70
  short* lnb_l = (short*)alloc((size_t)NT * DM * 2);       // 3.70
  char*  A1    = alloc((size_t)NT * 4 * DM * 4);           // 29.57: qkv h/l | predict scratch
  char*  A2    = alloc((size_t)NT * 4 * DM * 2);           // 14.78: ao h/l | g1h
  unsigned* bias_bits = (unsigned*)alloc((size_t)NQ * NWRD * 4);

  short* qkvh   = (short*)A1;                        // NT*3DM shorts
  short* qkvl   = qkvh + (size_t)NT * 3 * DM;        // NT*3DM shorts
  short* f1_h = (short*)A1;                          // predict scratch (first 2.46 MB)
  short* f1_l = f1_h + (size_t)NQ * DM;
  short* f2_h = f1_l + (size_t)NQ * DM;
  short* f2_l = f2_h + (size_t)NQ * DM;
  short* f3_h = f2_l + (size_t)NQ * DM;
  short* f3_l = f3_h + (size_t)NQ * DM;
  float* pbuf = (float*)(A1 + ((size_t)4 << 20));    // partials at A1+4MB (<=6.55MB)
  short* aoh   = (short*)A2;                         // NT*DM
  short* aol   = aoh + (size_t)NT * DM;
  short* g1h   = (short*)A2;                         // NT*4DM shorts (full A2; after proj)

  const int ELEM_GRID = (NT * DM + 255) / 256;
  auto g128 = [](int M, int Nc, int ks) { return dim3((Nc + 127) / 128, (M + 127) / 128, ks); };
  auto g64  = [](int M, int Nc, int ks) { return dim3((Nc + 127) / 128, (M + 63) / 64, ks); };
  auto rgrid = [](int n) { return dim3((n + 255) / 256); };

  concat_kernel<<<ELEM_GRID, 256, 0, stream>>>(q_weight, x_tokens, x);

  for (int i = 0; i <= NBLK; ++i) {
    // ---- predict head on shared-norm LN(x) ----
    ln_kernel<<<NT, 256, 0, stream>>>(x, norm_g, norm_b, lnb_h, lnb_l);
    float* mask_i = out + (size_t)i * NQ * NPATCH;
    float* cls_i  = out + (size_t)5 * NQ * NPATCH + (size_t)i * NQ * NCLS;
    mgemm_kernel<1, 0, 1, 0, 3, 8><<<g64(NQ, DM, 8), 256, 0, stream>>>(
        lnb_h, lnb_l, mask_W1, nullptr, nullptr, mask_b1, nullptr, pbuf, nullptr, nullptr, NQ, DM, DM);
    redsplit_kernel<1, 1><<<rgrid(NQ * DM), 256, 0, stream>>>(pbuf, nullptr, f1_h, f1_l, 8, NQ * DM);
    mgemm_kernel<1, 0, 1, 0, 3, 8><<<g64(NQ, DM, 8), 256, 0, stream>>>(
        f1_h, f1_l, mask_W2, nullptr, nullptr, mask_b2, nullptr, pbuf, nullptr, nullptr, NQ, DM, DM);
    redsplit_kernel<1, 1><<<rgrid(NQ * DM), 256, 0, stream>>>(pbuf, nullptr, f2_h, f2_l, 8, NQ * DM);
    mgemm_kernel<1, 0, 1, 0, 3, 8><<<g64(NQ, DM, 8), 256, 0, stream>>>(
        f2_h, f2_l, mask_W3, nullptr, nullptr, mask_b3, nullptr, pbuf, nullptr, nullptr, NQ, DM, DM);
    redsplit_kernel<0, 1><<<rgrid(NQ * DM), 256, 0, stream>>>(pbuf, nullptr, f3_h, f3_l, 8, NQ * DM);
    mgemm_kernel<1, 1, 1, 0, 3, 4><<<g64(NQ, NPATCH, 4), 256, 0, stream>>>(
        f3_h, f3_l, nullptr, lnb_h + (size_t)(NQ + PFX) * DM, lnb_l + (size_t)(NQ + PFX) * DM,
        nullptr, nullptr, pbuf, nullptr, nullptr, NQ, NPATCH, DM);
    redsplit_kernel<0, 0><<<rgrid(NQ * NPATCH), 256, 0, stream>>>(
        pbuf, mask_i, nullptr, nullptr, 4, NQ * NPATCH);
    mgemm_kernel<1, 0, 1, 0, 3, 8><<<g64(NQ, NCLS, 8), 256, 0, stream>>>(
        lnb_h, lnb_l, class_W, nullptr, nullptr, class_b, nullptr, pbuf, nullptr, nullptr, NQ, NCLS, DM);
    redsplit_kernel<0, 0><<<rgrid(NQ * NCLS), 256, 0, stream>>>(
        pbuf, cls_i, nullptr, nullptr, 8, NQ * NCLS);
    if (i == NBLK) break;

    // ---- transformer block i ----
    ln_kernel<<<NT, 256, 0, stream>>>(x, ln1_g + i * DM, ln1_b + i * DM, lnb_h, lnb_l);
    mgemm_kernel<0, 0, 1, 0, 0, 1><<<g128(NT, 3 * DM, 1), 256, 0, stream>>>(
        lnb_h, lnb_l, qkv_W + (size_t)i * DM * 3 * DM, nullptr, nullptr,
        qkv_b + i * 3 * DM, nullptr, nullptr, qkvh, qkvl, NT, 3 * DM, DM);
    maskpack_kernel<<<(NQ * NWRD + 255) / 256, 256, 0, stream>>>(mask_i, bias_bits);
    fattn_kernel<<<NKT * NHEAD, 256, 0, stream>>>(qkvh, qkvl, bias_bits, aoh, aol);
    // proj: fused layer-scale residual (x += ls1 * (ao @ W + b)), split-K atomic
    mgemm_kernel<1, 0, 1, 0, 5, 4><<<g64(NT, DM, 4), 256, 0, stream>>>(
        aoh, aol, proj_W + (size_t)i * DM * DM, nullptr, nullptr,
        proj_b + i * DM, ls1 + i * DM, x, nullptr, nullptr, NT, DM, DM);
    ln_kernel<<<NT, 256, 0, stream>>>(x, ln2_g + i * DM, ln2_b + i * DM, lnb_h, lnb_l);
    // fc1: KS=1, fused gelu + bf16-hi-only output (g1h)
    mgemm_kernel<0, 0, 1, 1, 4, 1><<<g128(NT, 4 * DM, 1), 256, 0, stream>>>(
        lnb_h, lnb_l, fc1_W + (size_t)i * DM * 4 * DM, nullptr, nullptr,
        fc1_b + i * 4 * DM, nullptr, nullptr, g1h, nullptr, NT, 4 * DM, DM);
    // fc2: fused layer-scale residual (x += ls2 * (g1 @ W + b)), split-K atomic
    mgemm_kernel<1, 0, 0, 0, 5, 4><<<g64(NT, DM, 4), 256, 0, stream>>>(
        g1h, nullptr, fc2_W + (size_t)i * 4 * DM * DM, nullptr, nullptr,
        fc2_b + i * DM, ls2 + i * DM, x, nullptr, nullptr, NT, DM, 4 * DM);
  }
}